// Round 1
// baseline (2164.494 us; speedup 1.0000x reference)
//
#include <hip/hip_runtime.h>
#include <math.h>

#define B_    2
#define T_    512
#define D_    512
#define E_    8
#define DI_   1024
#define DS_   16
#define DTR_  32
#define WIN_  64
#define BT_   (B_*T_)
#define BTD_  (BT_*D_)

// ---------- activation helpers ----------
__device__ __forceinline__ float gelu_f(float x) {
    // jax.nn.gelu default (approximate=True, tanh form)
    float x3 = x * x * x;
    return 0.5f * x * (1.0f + tanhf(0.7978845608028654f * (x + 0.044715f * x3)));
}
__device__ __forceinline__ float silu_f(float x) {
    return x / (1.0f + __expf(-x));
}
__device__ __forceinline__ float softplus_f(float x) {
    return (x > 20.0f) ? x : log1pf(__expf(x));
}

// ---------- RMSNorm + per-token mean (v) ----------
__global__ __launch_bounds__(256) void rmsnorm_kernel(
    const float* __restrict__ x, const float* __restrict__ nw,
    float* __restrict__ xn, float* __restrict__ v)
{
    int t = blockIdx.x;               // token index in [0, BT)
    const float* xr = x + (size_t)t * D_;
    float s = 0.f;
    for (int i = threadIdx.x; i < D_; i += 256) { float a = xr[i]; s += a * a; }
    __shared__ float sb[4];
    __shared__ float sb2[4];
    for (int o = 32; o > 0; o >>= 1) s += __shfl_down(s, o);
    if ((threadIdx.x & 63) == 0) sb[threadIdx.x >> 6] = s;
    __syncthreads();
    float tot = sb[0] + sb[1] + sb[2] + sb[3];
    float scale = rsqrtf(tot / (float)D_ + 1e-6f);
    float vs = 0.f;
    for (int i = threadIdx.x; i < D_; i += 256) {
        float a = xr[i] * scale * nw[i];
        xn[(size_t)t * D_ + i] = a;
        vs += a;
    }
    for (int o = 32; o > 0; o >>= 1) vs += __shfl_down(vs, o);
    if ((threadIdx.x & 63) == 0) sb2[threadIdx.x >> 6] = vs;
    __syncthreads();
    if (threadIdx.x == 0) v[t] = (sb2[0] + sb2[1] + sb2[2] + sb2[3]) / (float)D_;
}

// ---------- spectral entropy ----------
__global__ __launch_bounds__(256) void entropy_kernel(
    const float* __restrict__ v, float* __restrict__ ent)
{
    int b = blockIdx.x;
    __shared__ float c1[T_ + 1], c2[T_ + 1];
    if (threadIdx.x == 0) {
        float s1 = 0.f, s2 = 0.f;
        c1[0] = 0.f; c2[0] = 0.f;
        for (int t = 0; t < T_; ++t) {
            float a = v[b * T_ + t];
            s1 += a; s2 += a * a;
            c1[t + 1] = s1; c2[t + 1] = s2;
        }
    }
    __syncthreads();
    for (int t = threadIdx.x; t < T_; t += 256) {
        int j = t + 1 - WIN_;
        float p1 = (j > 0) ? c1[j] : 0.f;
        float p2 = (j > 0) ? c2[j] : 0.f;
        float mu  = (c1[t + 1] - p1) / (float)WIN_;
        float mu2 = (c2[t + 1] - p2) / (float)WIN_;
        float var = fmaxf(mu2 - mu * mu, 0.f);
        ent[b * T_ + t] = (logf(var + 1e-6f) + 10.f) / 20.f;
    }
}

// ---------- gating: logits, top-2, routing weights, aux accumulators ----------
__global__ __launch_bounds__(256) void gating_kernel(
    const float* __restrict__ xn, const float* __restrict__ gw,
    const float* __restrict__ ew, const float* __restrict__ eb,
    const float* __restrict__ temp, const float* __restrict__ ent,
    float* __restrict__ wm, float* __restrict__ red)
{
    int t = blockIdx.x;
    __shared__ float xs[D_];
    __shared__ float sbuf[4];
    __shared__ float lg[E_];
    for (int i = threadIdx.x; i < D_; i += 256) xs[i] = xn[(size_t)t * D_ + i];
    __syncthreads();
    for (int e = 0; e < E_; ++e) {
        float s = 0.f;
        for (int i = threadIdx.x; i < D_; i += 256) s += xs[i] * gw[e * D_ + i];
        for (int o = 32; o > 0; o >>= 1) s += __shfl_down(s, o);
        if ((threadIdx.x & 63) == 0) sbuf[threadIdx.x >> 6] = s;
        __syncthreads();
        if (threadIdx.x == 0) lg[e] = sbuf[0] + sbuf[1] + sbuf[2] + sbuf[3];
        __syncthreads();
    }
    if (threadIdx.x == 0) {
        float ev = ent[t];
        float ts = 1.f / (fabsf(temp[0]) + 1e-6f);
        float l[E_];
        for (int e = 0; e < E_; ++e) l[e] = (lg[e] + ev * ew[e] + eb[e]) * ts;
        // top-2 (first-occurrence on ties, matching jax.lax.top_k)
        int i1 = 0;
        for (int e = 1; e < E_; ++e) if (l[e] > l[i1]) i1 = e;
        int i2 = -1;
        for (int e = 0; e < E_; ++e) { if (e == i1) continue; if (i2 < 0 || l[e] > l[i2]) i2 = e; }
        float e2 = __expf(l[i2] - l[i1]);
        float Z = 1.f + e2;
        float r1 = 1.f / Z, r2 = e2 / Z;
        for (int e = 0; e < E_; ++e) wm[t * E_ + e] = 0.f;
        wm[t * E_ + i1] = r1;
        wm[t * E_ + i2] = r2;
        // full softmax for aux loss
        float mm = l[0];
        for (int e = 1; e < E_; ++e) mm = fmaxf(mm, l[e]);
        float p[E_]; float Zs = 0.f;
        for (int e = 0; e < E_; ++e) { p[e] = __expf(l[e] - mm); Zs += p[e]; }
        for (int e = 0; e < E_; ++e) atomicAdd(&red[E_ + e], p[e] / Zs);
        atomicAdd(&red[i1], 1.f);
        atomicAdd(&red[i2], 1.f);
    }
}

__global__ void aux_kernel(const float* __restrict__ red, float* __restrict__ out_aux)
{
    float s = 0.f;
    for (int e = 0; e < E_; ++e)
        s += (red[e] / (float)BT_) * (red[E_ + e] / (float)BT_);
    out_aux[0] = (float)E_ * s;
}

// ---------- generic tiled fp32 GEMM: C = act(A @ W^T + bias) ----------
// A: M x K (row stride lda). W: N x K (row stride ldw). C: M x N (row stride ldc).
// ACT: 0=none 1=gelu 2=softplus.  ACCUM: C[m,n] += val * wmv[m*E_]
template<int ACT, bool BIAS, bool ACCUM>
__global__ __launch_bounds__(256) void gemm_kernel(
    const float* __restrict__ A, int lda,
    const float* __restrict__ W, int ldw,
    const float* __restrict__ bias,
    float* __restrict__ C, int ldc,
    const float* __restrict__ wmv,
    int M, int N, int K)
{
    __shared__ float As[16][68];
    __shared__ float Ws[16][68];
    const int bm = blockIdx.y * 64, bn = blockIdx.x * 64;
    const int tid = threadIdx.x;
    const int tx = tid & 15, ty = tid >> 4;
    const int lm = tid >> 2, lk = (tid & 3) * 4;

    const float* Ap = A + (size_t)(bm + lm) * lda + lk;
    const float* Wp = W + (size_t)(bn + lm) * ldw + lk;

    float acc[4][4] = {};
    for (int k0 = 0; k0 < K; k0 += 16) {
        float4 av = *(const float4*)(Ap + k0);
        float4 wv = *(const float4*)(Wp + k0);
        __syncthreads();
        As[lk + 0][lm] = av.x; As[lk + 1][lm] = av.y;
        As[lk + 2][lm] = av.z; As[lk + 3][lm] = av.w;
        Ws[lk + 0][lm] = wv.x; Ws[lk + 1][lm] = wv.y;
        Ws[lk + 2][lm] = wv.z; Ws[lk + 3][lm] = wv.w;
        __syncthreads();
#pragma unroll
        for (int k = 0; k < 16; ++k) {
            float4 a = *(const float4*)&As[k][ty * 4];
            float4 w = *(const float4*)&Ws[k][tx * 4];
            acc[0][0] += a.x * w.x; acc[0][1] += a.x * w.y; acc[0][2] += a.x * w.z; acc[0][3] += a.x * w.w;
            acc[1][0] += a.y * w.x; acc[1][1] += a.y * w.y; acc[1][2] += a.y * w.z; acc[1][3] += a.y * w.w;
            acc[2][0] += a.z * w.x; acc[2][1] += a.z * w.y; acc[2][2] += a.z * w.z; acc[2][3] += a.z * w.w;
            acc[3][0] += a.w * w.x; acc[3][1] += a.w * w.y; acc[3][2] += a.w * w.z; acc[3][3] += a.w * w.w;
        }
    }
#pragma unroll
    for (int i = 0; i < 4; ++i) {
        int m = bm + ty * 4 + i;
        float wmval = ACCUM ? wmv[m * E_] : 0.f;
#pragma unroll
        for (int j = 0; j < 4; ++j) {
            int n = bn + tx * 4 + j;
            float val = acc[i][j];
            if (BIAS) val += bias[n];
            if (ACT == 1) val = gelu_f(val);
            else if (ACT == 2) val = softplus_f(val);
            if (ACCUM) C[(size_t)m * ldc + n] += val * wmval;
            else       C[(size_t)m * ldc + n] = val;
        }
    }
}

// ---------- depthwise causal conv, k=7, + bias + gelu ----------
__global__ __launch_bounds__(256) void dwconv7_kernel(
    const float* __restrict__ h, const float* __restrict__ w,
    const float* __restrict__ bias, float* __restrict__ g)
{
    int idx = blockIdx.x * 256 + threadIdx.x;     // [0, B*T*DI)
    int c = idx & (DI_ - 1);
    int t = (idx >> 10) & (T_ - 1);
    float acc = bias[c];
#pragma unroll
    for (int j = 0; j < 7; ++j) {
        int tt = t - 6 + j;
        if (tt >= 0) acc += h[idx + (j - 6) * DI_] * w[c * 7 + j];
    }
    g[idx] = gelu_f(acc);
}

// ---------- depthwise causal conv, k=4, input strided (u half of uz), + bias + silu ----------
__global__ __launch_bounds__(256) void dwconv4_kernel(
    const float* __restrict__ uz, const float* __restrict__ w,
    const float* __restrict__ bias, float* __restrict__ uc)
{
    int idx = blockIdx.x * 256 + threadIdx.x;     // [0, B*T*DI)
    int c = idx & (DI_ - 1);
    int t = (idx >> 10) & (T_ - 1);
    int bt = idx >> 10;                           // b*T + t
    const float* up = uz + (size_t)bt * 2048 + c;
    float acc = bias[c];
#pragma unroll
    for (int j = 0; j < 4; ++j) {
        int tt = t - 3 + j;
        if (tt >= 0) acc += up[(size_t)(j - 3) * 2048] * w[c * 4 + j];
    }
    uc[idx] = silu_f(acc);
}

// ---------- selective scan: one lane per (b, d, s); reduce over s (16 lanes) ----------
__global__ __launch_bounds__(256) void scan_kernel(
    const float* __restrict__ delta, const float* __restrict__ uc,
    const float* __restrict__ proj, const float* __restrict__ Alog,
    const float* __restrict__ Dm, float* __restrict__ y)
{
    int gid = blockIdx.x * 256 + threadIdx.x;     // [0, B*DI*16)
    int s = gid & 15;
    int d = (gid >> 4) & (DI_ - 1);
    int b = gid >> 14;
    float A = -expf(Alog[d * DS_ + s]);
    float Dd = Dm[d];
    float h = 0.f;
    const float* dp = delta + (size_t)b * T_ * DI_ + d;
    const float* up = uc    + (size_t)b * T_ * DI_ + d;
    const float* pp = proj  + (size_t)b * T_ * 64;
    float* yp = y + (size_t)b * T_ * DI_ + d;
    for (int t = 0; t < T_; ++t) {
        float del = dp[(size_t)t * DI_];
        float uv  = up[(size_t)t * DI_];
        float Bv  = pp[t * 64 + DTR_ + s];
        float Cv  = pp[t * 64 + DTR_ + DS_ + s];
        float dA = __expf(del * A);
        h = dA * h + del * Bv * uv;
        float p = h * Cv;
#pragma unroll
        for (int o = 8; o > 0; o >>= 1) p += __shfl_down(p, o, 16);
        if (s == 0) yp[(size_t)t * DI_] = p + uv * Dd;
    }
}

// ---------- y *= silu(z)  (z = second half of uz) ----------
__global__ __launch_bounds__(256) void prod_kernel(
    float* __restrict__ y, const float* __restrict__ uz)
{
    int idx = blockIdx.x * 256 + threadIdx.x;
    int c = idx & (DI_ - 1);
    int bt = idx >> 10;
    float z = uz[(size_t)bt * 2048 + DI_ + c];
    y[idx] *= silu_f(z);
}

extern "C" void kernel_launch(void* const* d_in, const int* in_sizes, int n_in,
                              void* d_out, int out_size, void* d_ws, size_t ws_size,
                              hipStream_t stream)
{
    const float* x      = (const float*)d_in[0];
    const float* norm_w = (const float*)d_in[1];
    const float* gate_w = (const float*)d_in[2];
    const float* ent_w  = (const float*)d_in[3];
    const float* ent_b  = (const float*)d_in[4];
    const float* temp   = (const float*)d_in[5];
    const float* cfi_w  = (const float*)d_in[6];
    const float* cfi_b  = (const float*)d_in[7];
    const float* cdw_w  = (const float*)d_in[8];
    const float* cdw_b  = (const float*)d_in[9];
    const float* cfo_w  = (const float*)d_in[10];
    const float* cfo_b  = (const float*)d_in[11];
    const float* min_w  = (const float*)d_in[12];
    const float* mcw    = (const float*)d_in[13];
    const float* mcb    = (const float*)d_in[14];
    const float* mxp    = (const float*)d_in[15];
    const float* mdtw   = (const float*)d_in[16];
    const float* mdtb   = (const float*)d_in[17];
    const float* mAlog  = (const float*)d_in[18];
    const float* mD     = (const float*)d_in[19];
    const float* mow    = (const float*)d_in[20];

    float* out = (float*)d_out;
    float* ws  = (float*)d_ws;

    // workspace layout (floats)
    float* xn    = ws;                       // 524288
    float* v     = xn + BTD_;                // 1024
    float* ent   = v + BT_;                  // 1024
    float* wm    = ent + BT_;                // 8192
    float* red   = wm + BT_ * E_;            // 16
    float* bufA  = red + 16;                 // 2097152: conv h|g, mamba uz
    float* h     = bufA;
    float* g     = bufA + (size_t)BT_ * DI_;
    float* uz    = bufA;
    float* uc    = bufA + 2 * (size_t)BT_ * DI_;   // 1048576
    float* proj  = uc + (size_t)BT_ * DI_;         // 65536
    float* delta = proj + (size_t)BT_ * 64;        // 1048576
    float* y     = delta + (size_t)BT_ * DI_;      // 1048576

    // out = residual; aux accumulators = 0
    hipMemcpyAsync(out, x, (size_t)BTD_ * sizeof(float), hipMemcpyDeviceToDevice, stream);
    hipMemsetAsync(red, 0, 16 * sizeof(float), stream);

    rmsnorm_kernel<<<BT_, 256, 0, stream>>>(x, norm_w, xn, v);
    entropy_kernel<<<B_, 256, 0, stream>>>(v, ent);
    gating_kernel<<<BT_, 256, 0, stream>>>(xn, gate_w, ent_w, ent_b, temp, ent, wm, red);
    aux_kernel<<<1, 1, 0, stream>>>(red, out + BTD_);

    const int NE = BT_ * DI_ / 256;  // 4096 blocks for elementwise over B*T*DI

    // ---- conv experts ----
    for (int e = 0; e < 4; ++e) {
        gemm_kernel<1, true, false><<<dim3(DI_ / 64, BT_ / 64), 256, 0, stream>>>(
            xn, D_, cfi_w + (size_t)e * DI_ * D_, D_, cfi_b + e * DI_,
            h, DI_, nullptr, BT_, DI_, D_);
        dwconv7_kernel<<<NE, 256, 0, stream>>>(
            h, cdw_w + (size_t)e * DI_ * 7, cdw_b + e * DI_, g);
        gemm_kernel<0, true, true><<<dim3(D_ / 64, BT_ / 64), 256, 0, stream>>>(
            g, DI_, cfo_w + (size_t)e * D_ * DI_, DI_, cfo_b + e * D_,
            out, D_, wm + e, BT_, D_, DI_);
    }

    // ---- mamba experts ----
    for (int m = 0; m < 4; ++m) {
        int e = 4 + m;
        gemm_kernel<0, false, false><<<dim3(2048 / 64, BT_ / 64), 256, 0, stream>>>(
            xn, D_, min_w + (size_t)m * 2048 * D_, D_, nullptr,
            uz, 2048, nullptr, BT_, 2048, D_);
        dwconv4_kernel<<<NE, 256, 0, stream>>>(
            uz, mcw + (size_t)m * DI_ * 4, mcb + m * DI_, uc);
        gemm_kernel<0, false, false><<<dim3(64 / 64, BT_ / 64), 256, 0, stream>>>(
            uc, DI_, mxp + (size_t)m * 64 * DI_, DI_, nullptr,
            proj, 64, nullptr, BT_, 64, DI_);
        gemm_kernel<2, true, false><<<dim3(DI_ / 64, BT_ / 64), 256, 0, stream>>>(
            proj, 64, mdtw + (size_t)m * DI_ * DTR_, DTR_, mdtb + m * DI_,
            delta, DI_, nullptr, BT_, DI_, DTR_);
        scan_kernel<<<B_ * DI_ * 16 / 256, 256, 0, stream>>>(
            delta, uc, proj, mAlog + (size_t)m * DI_ * DS_, mD + m * DI_, y);
        prod_kernel<<<NE, 256, 0, stream>>>(y, uz);
        gemm_kernel<0, false, true><<<dim3(D_ / 64, BT_ / 64), 256, 0, stream>>>(
            y, DI_, mow + (size_t)m * D_ * DI_, DI_, nullptr,
            out, D_, wm + e, BT_, D_, DI_);
    }
}

// Round 2
// 765.507 us; speedup vs baseline: 2.8275x; 2.8275x over previous
//
#include <hip/hip_runtime.h>
#include <math.h>

#define B_    2
#define T_    512
#define D_    512
#define E_    8
#define DI_   1024
#define DS_   16
#define DTR_  32
#define WIN_  64
#define BT_   (B_*T_)
#define BTD_  (BT_*D_)
#define NC_   16
#define LCH_  32    // T_/NC_

typedef unsigned short u16;
typedef __attribute__((ext_vector_type(8))) short bf16x8;
typedef __attribute__((ext_vector_type(4))) float f32x4;

// ---------- helpers ----------
__device__ __forceinline__ float gelu_f(float x) {
    float x3 = x * x * x;
    return 0.5f * x * (1.0f + tanhf(0.7978845608028654f * (x + 0.044715f * x3)));
}
__device__ __forceinline__ float silu_f(float x) {
    return x / (1.0f + __expf(-x));
}
__device__ __forceinline__ float softplus_f(float x) {
    return (x > 20.0f) ? x : log1pf(__expf(x));
}
__device__ __forceinline__ u16 f2bf(float x) {
    union { float f; unsigned u; } v; v.f = x;
    unsigned r = v.u + 0x7fffu + ((v.u >> 16) & 1u);
    return (u16)(r >> 16);
}
__device__ __forceinline__ void gload_lds16(const u16* g, u16* l) {
    __builtin_amdgcn_global_load_lds((const __attribute__((address_space(1))) void*)g,
                                     (__attribute__((address_space(3))) void*)l, 16, 0, 0);
}

// ---------- fp32 -> bf16 bulk convert (float4 in, ushort4 out) ----------
__global__ __launch_bounds__(256) void convert_bf16_kernel(
    const float4* __restrict__ src, u16* __restrict__ dst, int n4)
{
    int i = blockIdx.x * 256 + threadIdx.x;
    if (i < n4) {
        float4 v = src[i];
        ushort4 o;
        o.x = f2bf(v.x); o.y = f2bf(v.y); o.z = f2bf(v.z); o.w = f2bf(v.w);
        *(ushort4*)(dst + (size_t)i * 4) = o;
    }
}

// ---------- RMSNorm + bf16 copy + per-token mean (v) ----------
__global__ __launch_bounds__(256) void rmsnorm_kernel(
    const float* __restrict__ x, const float* __restrict__ nw,
    float* __restrict__ xn, u16* __restrict__ xnb, float* __restrict__ v)
{
    int t = blockIdx.x;
    const float* xr = x + (size_t)t * D_;
    float s = 0.f;
    for (int i = threadIdx.x; i < D_; i += 256) { float a = xr[i]; s += a * a; }
    __shared__ float sb[4];
    __shared__ float sb2[4];
    for (int o = 32; o > 0; o >>= 1) s += __shfl_down(s, o);
    if ((threadIdx.x & 63) == 0) sb[threadIdx.x >> 6] = s;
    __syncthreads();
    float tot = sb[0] + sb[1] + sb[2] + sb[3];
    float scale = rsqrtf(tot / (float)D_ + 1e-6f);
    float vs = 0.f;
    for (int i = threadIdx.x; i < D_; i += 256) {
        float a = xr[i] * scale * nw[i];
        xn[(size_t)t * D_ + i] = a;
        xnb[(size_t)t * D_ + i] = f2bf(a);
        vs += a;
    }
    for (int o = 32; o > 0; o >>= 1) vs += __shfl_down(vs, o);
    if ((threadIdx.x & 63) == 0) sb2[threadIdx.x >> 6] = vs;
    __syncthreads();
    if (threadIdx.x == 0) v[t] = (sb2[0] + sb2[1] + sb2[2] + sb2[3]) / (float)D_;
}

// ---------- spectral entropy ----------
__global__ __launch_bounds__(256) void entropy_kernel(
    const float* __restrict__ v, float* __restrict__ ent)
{
    int b = blockIdx.x;
    __shared__ float c1[T_ + 1], c2[T_ + 1];
    if (threadIdx.x == 0) {
        float s1 = 0.f, s2 = 0.f;
        c1[0] = 0.f; c2[0] = 0.f;
        for (int t = 0; t < T_; ++t) {
            float a = v[b * T_ + t];
            s1 += a; s2 += a * a;
            c1[t + 1] = s1; c2[t + 1] = s2;
        }
    }
    __syncthreads();
    for (int t = threadIdx.x; t < T_; t += 256) {
        int j = t + 1 - WIN_;
        float p1 = (j > 0) ? c1[j] : 0.f;
        float p2 = (j > 0) ? c2[j] : 0.f;
        float mu  = (c1[t + 1] - p1) / (float)WIN_;
        float mu2 = (c2[t + 1] - p2) / (float)WIN_;
        float var = fmaxf(mu2 - mu * mu, 0.f);
        ent[b * T_ + t] = (logf(var + 1e-6f) + 10.f) / 20.f;
    }
}

// ---------- gating ----------
__global__ __launch_bounds__(256) void gating_kernel(
    const float* __restrict__ xn, const float* __restrict__ gw,
    const float* __restrict__ ew, const float* __restrict__ eb,
    const float* __restrict__ temp, const float* __restrict__ ent,
    float* __restrict__ wm, float* __restrict__ red)
{
    int t = blockIdx.x;
    __shared__ float xs[D_];
    __shared__ float sbuf[4];
    __shared__ float lg[E_];
    for (int i = threadIdx.x; i < D_; i += 256) xs[i] = xn[(size_t)t * D_ + i];
    __syncthreads();
    for (int e = 0; e < E_; ++e) {
        float s = 0.f;
        for (int i = threadIdx.x; i < D_; i += 256) s += xs[i] * gw[e * D_ + i];
        for (int o = 32; o > 0; o >>= 1) s += __shfl_down(s, o);
        if ((threadIdx.x & 63) == 0) sbuf[threadIdx.x >> 6] = s;
        __syncthreads();
        if (threadIdx.x == 0) lg[e] = sbuf[0] + sbuf[1] + sbuf[2] + sbuf[3];
        __syncthreads();
    }
    if (threadIdx.x == 0) {
        float ev = ent[t];
        float ts = 1.f / (fabsf(temp[0]) + 1e-6f);
        float l[E_];
        for (int e = 0; e < E_; ++e) l[e] = (lg[e] + ev * ew[e] + eb[e]) * ts;
        int i1 = 0;
        for (int e = 1; e < E_; ++e) if (l[e] > l[i1]) i1 = e;
        int i2 = -1;
        for (int e = 0; e < E_; ++e) { if (e == i1) continue; if (i2 < 0 || l[e] > l[i2]) i2 = e; }
        float e2 = __expf(l[i2] - l[i1]);
        float Z = 1.f + e2;
        float r1 = 1.f / Z, r2 = e2 / Z;
        for (int e = 0; e < E_; ++e) wm[t * E_ + e] = 0.f;
        wm[t * E_ + i1] = r1;
        wm[t * E_ + i2] = r2;
        float mm = l[0];
        for (int e = 1; e < E_; ++e) mm = fmaxf(mm, l[e]);
        float p[E_]; float Zs = 0.f;
        for (int e = 0; e < E_; ++e) { p[e] = __expf(l[e] - mm); Zs += p[e]; }
        for (int e = 0; e < E_; ++e) atomicAdd(&red[E_ + e], p[e] / Zs);
        atomicAdd(&red[i1], 1.f);
        atomicAdd(&red[i2], 1.f);
    }
}

__global__ void aux_kernel(const float* __restrict__ red, float* __restrict__ out_aux)
{
    float s = 0.f;
    for (int e = 0; e < E_; ++e)
        s += (red[e] / (float)BT_) * (red[E_ + e] / (float)BT_);
    out_aux[0] = (float)E_ * s;
}

// ---------- bf16 MFMA GEMM: C = act(A @ W^T + bias) [* wm accumulate] ----------
// A: M x K bf16 row-major. W: N x K bf16 row-major. C: M x N fp32.
// Tile 64x64, 4 waves (2x2 of 32x32), BK=64, global_load_lds staging with XOR
// chunk swizzle (row r, 16B chunk q stored at slot q^(r&7)) -> 2-way LDS reads.
template<int ACT, bool BIAS, bool ACCUM>
__global__ __launch_bounds__(256) void mfma_gemm_kernel(
    const u16* __restrict__ A, int lda,
    const u16* __restrict__ W, int ldw,
    const float* __restrict__ bias,
    float* __restrict__ C, int ldc,
    const float* __restrict__ wmv,
    int K)
{
    __shared__ u16 As[64 * 64];
    __shared__ u16 Bs[64 * 64];
    const int tid  = threadIdx.x;
    const int wave = tid >> 6;
    const int lane = tid & 63;
    const int quad = lane >> 4;
    const int r16  = lane & 15;
    const int bm = blockIdx.y * 64;
    const int bn = blockIdx.x * 64;
    const int wm = (wave >> 1) * 32;
    const int wn = (wave & 1) * 32;

    // staging: slot s holds 16B; row = s>>3, physical chunk p = s&7 contains
    // logical chunk q = p ^ (row&7). Each thread stages 2 chunks of A, 2 of B.
    const int s0 = tid, s1 = 256 + tid;
    const int r0 = s0 >> 3, q0 = (s0 & 7) ^ (r0 & 7);
    const int r1 = s1 >> 3, q1 = (s1 & 7) ^ (r1 & 7);
    const u16* Ag0 = A + (size_t)(bm + r0) * lda + q0 * 8;
    const u16* Ag1 = A + (size_t)(bm + r1) * lda + q1 * 8;
    const u16* Wg0 = W + (size_t)(bn + r0) * ldw + q0 * 8;
    const u16* Wg1 = W + (size_t)(bn + r1) * ldw + q1 * 8;
    u16* Al0 = As + wave * 512;
    u16* Al1 = As + 2048 + wave * 512;
    u16* Bl0 = Bs + wave * 512;
    u16* Bl1 = Bs + 2048 + wave * 512;

    f32x4 acc[2][2];
    const f32x4 zero = {0.f, 0.f, 0.f, 0.f};
    acc[0][0] = zero; acc[0][1] = zero; acc[1][0] = zero; acc[1][1] = zero;

    for (int k0 = 0; k0 < K; k0 += 64) {
        gload_lds16(Ag0 + k0, Al0);
        gload_lds16(Ag1 + k0, Al1);
        gload_lds16(Wg0 + k0, Bl0);
        gload_lds16(Wg1 + k0, Bl1);
        __syncthreads();   // drains vmcnt before LDS reads
#pragma unroll
        for (int ks = 0; ks < 2; ++ks) {
            bf16x8 af[2], bfr[2];
#pragma unroll
            for (int mi = 0; mi < 2; ++mi) {
                int row = wm + mi * 16 + r16;
                int p = (ks * 4 + quad) ^ (row & 7);
                af[mi] = *(const bf16x8*)(As + row * 64 + p * 8);
            }
#pragma unroll
            for (int ni = 0; ni < 2; ++ni) {
                int row = wn + ni * 16 + r16;
                int p = (ks * 4 + quad) ^ (row & 7);
                bfr[ni] = *(const bf16x8*)(Bs + row * 64 + p * 8);
            }
#pragma unroll
            for (int mi = 0; mi < 2; ++mi)
#pragma unroll
                for (int ni = 0; ni < 2; ++ni)
                    acc[mi][ni] = __builtin_amdgcn_mfma_f32_16x16x32_bf16(
                        af[mi], bfr[ni], acc[mi][ni], 0, 0, 0);
        }
        __syncthreads();
    }

    // C/D layout: row = quad*4 + reg, col = lane&15
#pragma unroll
    for (int mi = 0; mi < 2; ++mi) {
#pragma unroll
        for (int vv = 0; vv < 4; ++vv) {
            int m = bm + wm + mi * 16 + quad * 4 + vv;
            float wmval = ACCUM ? wmv[m * E_] : 0.f;
#pragma unroll
            for (int ni = 0; ni < 2; ++ni) {
                int n = bn + wn + ni * 16 + r16;
                float val = acc[mi][ni][vv];
                if (BIAS) val += bias[n];
                if (ACT == 1) val = gelu_f(val);
                if (ACCUM) C[(size_t)m * ldc + n] += val * wmval;
                else       C[(size_t)m * ldc + n] = val;
            }
        }
    }
}

// ---------- fp32 tiled GEMM (kept for dt-proj, K=32) ----------
template<int ACT, bool BIAS, bool ACCUM>
__global__ __launch_bounds__(256) void gemm_kernel(
    const float* __restrict__ A, int lda,
    const float* __restrict__ W, int ldw,
    const float* __restrict__ bias,
    float* __restrict__ C, int ldc,
    const float* __restrict__ wmv,
    int M, int N, int K)
{
    __shared__ float As[16][68];
    __shared__ float Ws[16][68];
    const int bm = blockIdx.y * 64, bn = blockIdx.x * 64;
    const int tid = threadIdx.x;
    const int tx = tid & 15, ty = tid >> 4;
    const int lm = tid >> 2, lk = (tid & 3) * 4;

    const float* Ap = A + (size_t)(bm + lm) * lda + lk;
    const float* Wp = W + (size_t)(bn + lm) * ldw + lk;

    float acc[4][4] = {};
    for (int k0 = 0; k0 < K; k0 += 16) {
        float4 av = *(const float4*)(Ap + k0);
        float4 wv = *(const float4*)(Wp + k0);
        __syncthreads();
        As[lk + 0][lm] = av.x; As[lk + 1][lm] = av.y;
        As[lk + 2][lm] = av.z; As[lk + 3][lm] = av.w;
        Ws[lk + 0][lm] = wv.x; Ws[lk + 1][lm] = wv.y;
        Ws[lk + 2][lm] = wv.z; Ws[lk + 3][lm] = wv.w;
        __syncthreads();
#pragma unroll
        for (int k = 0; k < 16; ++k) {
            float4 a = *(const float4*)&As[k][ty * 4];
            float4 w = *(const float4*)&Ws[k][tx * 4];
            acc[0][0] += a.x * w.x; acc[0][1] += a.x * w.y; acc[0][2] += a.x * w.z; acc[0][3] += a.x * w.w;
            acc[1][0] += a.y * w.x; acc[1][1] += a.y * w.y; acc[1][2] += a.y * w.z; acc[1][3] += a.y * w.w;
            acc[2][0] += a.z * w.x; acc[2][1] += a.z * w.y; acc[2][2] += a.z * w.z; acc[2][3] += a.z * w.w;
            acc[3][0] += a.w * w.x; acc[3][1] += a.w * w.y; acc[3][2] += a.w * w.z; acc[3][3] += a.w * w.w;
        }
    }
#pragma unroll
    for (int i = 0; i < 4; ++i) {
        int m = bm + ty * 4 + i;
        float wmval = ACCUM ? wmv[m * E_] : 0.f;
#pragma unroll
        for (int j = 0; j < 4; ++j) {
            int n = bn + tx * 4 + j;
            float val = acc[i][j];
            if (BIAS) val += bias[n];
            if (ACT == 1) val = gelu_f(val);
            else if (ACT == 2) val = softplus_f(val);
            if (ACCUM) C[(size_t)m * ldc + n] += val * wmval;
            else       C[(size_t)m * ldc + n] = val;
        }
    }
}

// ---------- depthwise causal conv k=7 + bias + gelu, bf16 out ----------
__global__ __launch_bounds__(256) void dwconv7_kernel(
    const float* __restrict__ h, const float* __restrict__ w,
    const float* __restrict__ bias, u16* __restrict__ g)
{
    int idx = blockIdx.x * 256 + threadIdx.x;
    int c = idx & (DI_ - 1);
    int t = (idx >> 10) & (T_ - 1);
    float acc = bias[c];
#pragma unroll
    for (int j = 0; j < 7; ++j) {
        int tt = t - 6 + j;
        if (tt >= 0) acc += h[idx + (j - 6) * DI_] * w[c * 7 + j];
    }
    g[idx] = f2bf(gelu_f(acc));
}

// ---------- depthwise causal conv k=4 + bias + silu, f32 + bf16 out ----------
__global__ __launch_bounds__(256) void dwconv4_kernel(
    const float* __restrict__ uz, const float* __restrict__ w,
    const float* __restrict__ bias, float* __restrict__ uc, u16* __restrict__ ucb)
{
    int idx = blockIdx.x * 256 + threadIdx.x;
    int c = idx & (DI_ - 1);
    int t = (idx >> 10) & (T_ - 1);
    int bt = idx >> 10;
    const float* up = uz + (size_t)bt * 2048 + c;
    float acc = bias[c];
#pragma unroll
    for (int j = 0; j < 4; ++j) {
        int tt = t - 3 + j;
        if (tt >= 0) acc += up[(size_t)(j - 3) * 2048] * w[c * 4 + j];
    }
    float r = silu_f(acc);
    uc[idx] = r;
    ucb[idx] = f2bf(r);
}

// ---------- chunked selective scan ----------
// gid = ((b*NC + c)*DI + d)*16 + s ; chunk c covers t in [c*LCH, (c+1)*LCH)
__global__ __launch_bounds__(256) void scan1_kernel(
    const float* __restrict__ delta, const float* __restrict__ uc,
    const float* __restrict__ proj, const float* __restrict__ Alog,
    float* __restrict__ P, float* __restrict__ He)
{
    int gid = blockIdx.x * 256 + threadIdx.x;
    int s = gid & 15;
    int d = (gid >> 4) & (DI_ - 1);
    int c = (gid >> 14) & (NC_ - 1);
    int b = gid >> 18;
    float A = -__expf(Alog[d * DS_ + s]);
    int t0 = c * LCH_;
    const float* dp = delta + ((size_t)b * T_ + t0) * DI_ + d;
    const float* up = uc    + ((size_t)b * T_ + t0) * DI_ + d;
    const float* pp = proj  + ((size_t)b * T_ + t0) * 64;
    float h = 0.f, Pr = 1.f;
    for (int t = 0; t < LCH_; ++t) {
        float del = dp[(size_t)t * DI_];
        float uv  = up[(size_t)t * DI_];
        float Bv  = pp[t * 64 + DTR_ + s];
        float dA = __expf(del * A);
        h = dA * h + del * Bv * uv;
        Pr *= dA;
    }
    P[gid] = Pr;
    He[gid] = h;
}

__global__ __launch_bounds__(256) void scan_mid_kernel(
    const float* __restrict__ P, const float* __restrict__ He, float* __restrict__ H)
{
    int gid = blockIdx.x * 256 + threadIdx.x;   // (b*DI + d)*16 + s
    int ds16 = gid & (DI_ * 16 - 1);
    int b = gid >> 14;
    float h = 0.f;
    for (int c = 0; c < NC_; ++c) {
        size_t idx = (size_t)(b * NC_ + c) * DI_ * 16 + ds16;
        H[idx] = h;
        h = He[idx] + P[idx] * h;
    }
}

__global__ __launch_bounds__(256) void scan2_kernel(
    const float* __restrict__ delta, const float* __restrict__ uc,
    const float* __restrict__ proj, const float* __restrict__ Alog,
    const float* __restrict__ Dm, const float* __restrict__ H,
    float* __restrict__ y)
{
    int gid = blockIdx.x * 256 + threadIdx.x;
    int s = gid & 15;
    int d = (gid >> 4) & (DI_ - 1);
    int c = (gid >> 14) & (NC_ - 1);
    int b = gid >> 18;
    float A = -__expf(Alog[d * DS_ + s]);
    float Dd = Dm[d];
    int t0 = c * LCH_;
    const float* dp = delta + ((size_t)b * T_ + t0) * DI_ + d;
    const float* up = uc    + ((size_t)b * T_ + t0) * DI_ + d;
    const float* pp = proj  + ((size_t)b * T_ + t0) * 64;
    float* yp = y + ((size_t)b * T_ + t0) * DI_ + d;
    float h = H[gid];
    for (int t = 0; t < LCH_; ++t) {
        float del = dp[(size_t)t * DI_];
        float uv  = up[(size_t)t * DI_];
        float Bv  = pp[t * 64 + DTR_ + s];
        float Cv  = pp[t * 64 + DTR_ + DS_ + s];
        float dA = __expf(del * A);
        h = dA * h + del * Bv * uv;
        float p = h * Cv;
#pragma unroll
        for (int o = 8; o > 0; o >>= 1) p += __shfl_down(p, o, 16);
        if (s == 0) yp[(size_t)t * DI_] = p + uv * Dd;
    }
}

// ---------- yb = bf16( y * silu(z) ) ----------
__global__ __launch_bounds__(256) void prod_kernel(
    const float* __restrict__ y, const float* __restrict__ uz, u16* __restrict__ yb)
{
    int idx = blockIdx.x * 256 + threadIdx.x;
    int c = idx & (DI_ - 1);
    int bt = idx >> 10;
    float z = uz[(size_t)bt * 2048 + DI_ + c];
    yb[idx] = f2bf(y[idx] * silu_f(z));
}

extern "C" void kernel_launch(void* const* d_in, const int* in_sizes, int n_in,
                              void* d_out, int out_size, void* d_ws, size_t ws_size,
                              hipStream_t stream)
{
    const float* x      = (const float*)d_in[0];
    const float* norm_w = (const float*)d_in[1];
    const float* gate_w = (const float*)d_in[2];
    const float* ent_w  = (const float*)d_in[3];
    const float* ent_b  = (const float*)d_in[4];
    const float* temp   = (const float*)d_in[5];
    const float* cfi_w  = (const float*)d_in[6];
    const float* cfi_b  = (const float*)d_in[7];
    const float* cdw_w  = (const float*)d_in[8];
    const float* cdw_b  = (const float*)d_in[9];
    const float* cfo_w  = (const float*)d_in[10];
    const float* cfo_b  = (const float*)d_in[11];
    const float* min_w  = (const float*)d_in[12];
    const float* mcw    = (const float*)d_in[13];
    const float* mcb    = (const float*)d_in[14];
    const float* mxp    = (const float*)d_in[15];
    const float* mdtw   = (const float*)d_in[16];
    const float* mdtb   = (const float*)d_in[17];
    const float* mAlog  = (const float*)d_in[18];
    const float* mD     = (const float*)d_in[19];
    const float* mow    = (const float*)d_in[20];

    float* out = (float*)d_out;

    // ---- bump allocator over d_ws ----
    char* wp = (char*)d_ws;
    auto alloc = [&](size_t bytes) { char* r = wp; wp += (bytes + 255) & ~(size_t)255; return r; };

    float* xn   = (float*)alloc(BTD_ * 4);
    u16*   xnb  = (u16*)  alloc(BTD_ * 2);
    float* v    = (float*)alloc(BT_ * 4);
    float* ent  = (float*)alloc(BT_ * 4);
    float* wm   = (float*)alloc(BT_ * E_ * 4);
    float* red  = (float*)alloc(16 * 4);
    // bf16 weight copies
    u16* cfi_b16 = (u16*)alloc((size_t)4 * DI_ * D_ * 2);      // 4 MB
    u16* cfo_b16 = (u16*)alloc((size_t)4 * D_ * DI_ * 2);      // 4 MB
    u16* min_b16 = (u16*)alloc((size_t)4 * 2048 * D_ * 2);     // 8 MB
    u16* mxp_b16 = (u16*)alloc((size_t)4 * 64 * DI_ * 2);      // 0.5 MB
    u16* mow_b16 = (u16*)alloc((size_t)4 * D_ * DI_ * 2);      // 4 MB
    // conv pool
    float* h    = (float*)alloc((size_t)BT_ * DI_ * 4);        // 4 MB
    u16*   g    = (u16*)  alloc((size_t)BT_ * DI_ * 2);        // 2 MB
    // mamba pool
    float* uz    = (float*)alloc((size_t)BT_ * 2048 * 4);      // 8 MB
    float* uc    = (float*)alloc((size_t)BT_ * DI_ * 4);       // 4 MB
    u16*   ucb   = (u16*)  alloc((size_t)BT_ * DI_ * 2);       // 2 MB
    float* proj  = (float*)alloc((size_t)BT_ * 64 * 4);        // 256 KB
    float* delta = (float*)alloc((size_t)BT_ * DI_ * 4);       // 4 MB
    float* yv    = (float*)alloc((size_t)BT_ * DI_ * 4);       // 4 MB
    u16*   yb    = (u16*)  alloc((size_t)BT_ * DI_ * 2);       // 2 MB
    float* sP    = (float*)alloc((size_t)B_ * NC_ * DI_ * 16 * 4);  // 2 MB
    float* sHe   = (float*)alloc((size_t)B_ * NC_ * DI_ * 16 * 4);  // 2 MB
    float* sH    = (float*)alloc((size_t)B_ * NC_ * DI_ * 16 * 4);  // 2 MB

    // residual + aux init
    hipMemcpyAsync(out, x, (size_t)BTD_ * sizeof(float), hipMemcpyDeviceToDevice, stream);
    hipMemsetAsync(red, 0, 16 * sizeof(float), stream);

    // weight conversions
    {
        int n4;
        n4 = 4 * DI_ * D_ / 4;
        convert_bf16_kernel<<<(n4 + 255) / 256, 256, 0, stream>>>((const float4*)cfi_w, cfi_b16, n4);
        n4 = 4 * D_ * DI_ / 4;
        convert_bf16_kernel<<<(n4 + 255) / 256, 256, 0, stream>>>((const float4*)cfo_w, cfo_b16, n4);
        n4 = 4 * 2048 * D_ / 4;
        convert_bf16_kernel<<<(n4 + 255) / 256, 256, 0, stream>>>((const float4*)min_w, min_b16, n4);
        n4 = 4 * 64 * DI_ / 4;
        convert_bf16_kernel<<<(n4 + 255) / 256, 256, 0, stream>>>((const float4*)mxp, mxp_b16, n4);
        n4 = 4 * D_ * DI_ / 4;
        convert_bf16_kernel<<<(n4 + 255) / 256, 256, 0, stream>>>((const float4*)mow, mow_b16, n4);
    }

    rmsnorm_kernel<<<BT_, 256, 0, stream>>>(x, norm_w, xn, xnb, v);
    entropy_kernel<<<B_, 256, 0, stream>>>(v, ent);
    gating_kernel<<<BT_, 256, 0, stream>>>(xn, gate_w, ent_w, ent_b, temp, ent, wm, red);
    aux_kernel<<<1, 1, 0, stream>>>(red, out + BTD_);

    const int NE = BT_ * DI_ / 256;     // 4096 blocks
    const int NSC = B_ * NC_ * DI_ * 16 / 256;   // 2048 blocks

    // ---- conv experts ----
    for (int e = 0; e < 4; ++e) {
        mfma_gemm_kernel<1, true, false><<<dim3(DI_ / 64, BT_ / 64), 256, 0, stream>>>(
            xnb, D_, cfi_b16 + (size_t)e * DI_ * D_, D_, cfi_b + e * DI_,
            h, DI_, nullptr, D_);
        dwconv7_kernel<<<NE, 256, 0, stream>>>(
            h, cdw_w + (size_t)e * DI_ * 7, cdw_b + e * DI_, g);
        mfma_gemm_kernel<0, true, true><<<dim3(D_ / 64, BT_ / 64), 256, 0, stream>>>(
            g, DI_, cfo_b16 + (size_t)e * D_ * DI_, DI_, cfo_b + e * D_,
            out, D_, wm + e, DI_);
    }

    // ---- mamba experts ----
    for (int m = 0; m < 4; ++m) {
        int e = 4 + m;
        mfma_gemm_kernel<0, false, false><<<dim3(2048 / 64, BT_ / 64), 256, 0, stream>>>(
            xnb, D_, min_b16 + (size_t)m * 2048 * D_, D_, nullptr,
            uz, 2048, nullptr, D_);
        dwconv4_kernel<<<NE, 256, 0, stream>>>(
            uz, mcw + (size_t)m * DI_ * 4, mcb + m * DI_, uc, ucb);
        mfma_gemm_kernel<0, false, false><<<dim3(64 / 64, BT_ / 64), 256, 0, stream>>>(
            ucb, DI_, mxp_b16 + (size_t)m * 64 * DI_, DI_, nullptr,
            proj, 64, nullptr, DI_);
        gemm_kernel<2, true, false><<<dim3(DI_ / 64, BT_ / 64), 256, 0, stream>>>(
            proj, 64, mdtw + (size_t)m * DI_ * DTR_, DTR_, mdtb + m * DI_,
            delta, DI_, nullptr, BT_, DI_, DTR_);
        scan1_kernel<<<NSC, 256, 0, stream>>>(
            delta, uc, proj, mAlog + (size_t)m * DI_ * DS_, sP, sHe);
        scan_mid_kernel<<<B_ * DI_ * 16 / 256, 256, 0, stream>>>(sP, sHe, sH);
        scan2_kernel<<<NSC, 256, 0, stream>>>(
            delta, uc, proj, mAlog + (size_t)m * DI_ * DS_, mD + m * DI_, sH, yv);
        prod_kernel<<<NE, 256, 0, stream>>>(yv, uz, yb);
        mfma_gemm_kernel<0, false, true><<<dim3(D_ / 64, BT_ / 64), 256, 0, stream>>>(
            yb, DI_, mow_b16 + (size_t)m * D_ * DI_, DI_, nullptr,
            out, D_, wm + e, DI_);
    }
}

// Round 3
// 481.968 us; speedup vs baseline: 4.4909x; 1.5883x over previous
//
#include <hip/hip_runtime.h>
#include <math.h>

#define B_    2
#define T_    512
#define D_    512
#define E_    8
#define DI_   1024
#define DS_   16
#define DTR_  32
#define WIN_  64
#define BT_   (B_*T_)
#define BTD_  (BT_*D_)
#define NC_   16
#define LCH_  32    // T_/NC_

typedef unsigned short u16;
typedef __attribute__((ext_vector_type(8))) short bf16x8;
typedef __attribute__((ext_vector_type(4))) float f32x4;

// ---------- helpers ----------
__device__ __forceinline__ float gelu_f(float x) {
    float x3 = x * x * x;
    return 0.5f * x * (1.0f + tanhf(0.7978845608028654f * (x + 0.044715f * x3)));
}
__device__ __forceinline__ float silu_f(float x) {
    return x / (1.0f + __expf(-x));
}
__device__ __forceinline__ float softplus_f(float x) {
    return (x > 20.0f) ? x : log1pf(__expf(x));
}
__device__ __forceinline__ u16 f2bf(float x) {
    union { float f; unsigned u; } v; v.f = x;
    unsigned r = v.u + 0x7fffu + ((v.u >> 16) & 1u);
    return (u16)(r >> 16);
}
__device__ __forceinline__ float bf2f(u16 x) {
    union { unsigned u; float f; } v; v.u = ((unsigned)x) << 16; return v.f;
}
__device__ __forceinline__ void gload_lds16(const u16* g, u16* l) {
    __builtin_amdgcn_global_load_lds((const __attribute__((address_space(1))) void*)g,
                                     (__attribute__((address_space(3))) void*)l, 16, 0, 0);
}

// ---------- merged weight convert: cfi|cfo|min|mxp|mow -> one bf16 pool ----------
#define CB0_ 524288
#define CB1_ 1048576
#define CB2_ 2097152
#define CB3_ 2162688
#define CB4_ 2686976
__global__ __launch_bounds__(256) void convert_weights_kernel(
    const float4* __restrict__ s0, const float4* __restrict__ s1,
    const float4* __restrict__ s2, const float4* __restrict__ s3,
    const float4* __restrict__ s4, u16* __restrict__ dst)
{
    int i = blockIdx.x * 256 + threadIdx.x;
    if (i >= CB4_) return;
    const float4* src; int off;
    if      (i < CB0_) { src = s0; off = i; }
    else if (i < CB1_) { src = s1; off = i - CB0_; }
    else if (i < CB2_) { src = s2; off = i - CB1_; }
    else if (i < CB3_) { src = s3; off = i - CB2_; }
    else               { src = s4; off = i - CB3_; }
    float4 v = src[off];
    ushort4 o;
    o.x = f2bf(v.x); o.y = f2bf(v.y); o.z = f2bf(v.z); o.w = f2bf(v.w);
    *(ushort4*)(dst + (size_t)i * 4) = o;
}

// ---------- RMSNorm + bf16 copy + per-token mean (v) ----------
__global__ __launch_bounds__(256) void rmsnorm_kernel(
    const float* __restrict__ x, const float* __restrict__ nw,
    float* __restrict__ xn, u16* __restrict__ xnb, float* __restrict__ v)
{
    int t = blockIdx.x;
    const float* xr = x + (size_t)t * D_;
    float s = 0.f;
    for (int i = threadIdx.x; i < D_; i += 256) { float a = xr[i]; s += a * a; }
    __shared__ float sb[4];
    __shared__ float sb2[4];
    for (int o = 32; o > 0; o >>= 1) s += __shfl_down(s, o);
    if ((threadIdx.x & 63) == 0) sb[threadIdx.x >> 6] = s;
    __syncthreads();
    float tot = sb[0] + sb[1] + sb[2] + sb[3];
    float scale = rsqrtf(tot / (float)D_ + 1e-6f);
    float vs = 0.f;
    for (int i = threadIdx.x; i < D_; i += 256) {
        float a = xr[i] * scale * nw[i];
        xn[(size_t)t * D_ + i] = a;
        xnb[(size_t)t * D_ + i] = f2bf(a);
        vs += a;
    }
    for (int o = 32; o > 0; o >>= 1) vs += __shfl_down(vs, o);
    if ((threadIdx.x & 63) == 0) sb2[threadIdx.x >> 6] = vs;
    __syncthreads();
    if (threadIdx.x == 0) v[t] = (sb2[0] + sb2[1] + sb2[2] + sb2[3]) / (float)D_;
}

// ---------- spectral entropy: parallel prefix scan, 512 threads per batch ----------
__global__ __launch_bounds__(512) void entropy_kernel(
    const float* __restrict__ v, float* __restrict__ ent)
{
    int b = blockIdx.x;
    int t = threadIdx.x;
    __shared__ float a1[T_], a2[T_];
    float x = v[b * T_ + t];
    a1[t] = x; a2[t] = x * x;
    __syncthreads();
    for (int off = 1; off < T_; off <<= 1) {
        float t1 = (t >= off) ? a1[t - off] : 0.f;
        float t2 = (t >= off) ? a2[t - off] : 0.f;
        __syncthreads();
        a1[t] += t1; a2[t] += t2;
        __syncthreads();
    }
    float p1 = (t >= WIN_) ? a1[t - WIN_] : 0.f;
    float p2 = (t >= WIN_) ? a2[t - WIN_] : 0.f;
    float mu  = (a1[t] - p1) / (float)WIN_;
    float mu2 = (a2[t] - p2) / (float)WIN_;
    float var = fmaxf(mu2 - mu * mu, 0.f);
    ent[b * T_ + t] = (logf(var + 1e-6f) + 10.f) / 20.f;
}

// ---------- gating: one wave per token, no global atomics ----------
__global__ __launch_bounds__(256) void gating_kernel(
    const float* __restrict__ xn, const float* __restrict__ gw,
    const float* __restrict__ ew, const float* __restrict__ eb,
    const float* __restrict__ temp, const float* __restrict__ ent,
    float* __restrict__ wm, float* __restrict__ probs)
{
    int wave = threadIdx.x >> 6, lane = threadIdx.x & 63;
    int t = blockIdx.x * 4 + wave;
    const float* xr = xn + (size_t)t * D_;
    float l[E_];
#pragma unroll
    for (int e = 0; e < E_; ++e) {
        float s = 0.f;
        for (int i = lane; i < D_; i += 64) s += xr[i] * gw[e * D_ + i];
#pragma unroll
        for (int o = 32; o > 0; o >>= 1) s += __shfl_down(s, o);
        l[e] = s;
    }
    if (lane == 0) {
        float ev = ent[t];
        float ts = 1.f / (fabsf(temp[0]) + 1e-6f);
#pragma unroll
        for (int e = 0; e < E_; ++e) l[e] = (l[e] + ev * ew[e] + eb[e]) * ts;
        int i1 = 0;
        for (int e = 1; e < E_; ++e) if (l[e] > l[i1]) i1 = e;
        int i2 = -1;
        for (int e = 0; e < E_; ++e) { if (e == i1) continue; if (i2 < 0 || l[e] > l[i2]) i2 = e; }
        float e2 = __expf(l[i2] - l[i1]);
        float Z = 1.f + e2;
#pragma unroll
        for (int e = 0; e < E_; ++e) wm[t * E_ + e] = 0.f;
        wm[t * E_ + i1] = 1.f / Z;
        wm[t * E_ + i2] = e2 / Z;
        float mm = l[0];
        for (int e = 1; e < E_; ++e) mm = fmaxf(mm, l[e]);
        float Zs = 0.f; float p[E_];
#pragma unroll
        for (int e = 0; e < E_; ++e) { p[e] = __expf(l[e] - mm); Zs += p[e]; }
#pragma unroll
        for (int e = 0; e < E_; ++e) probs[t * E_ + e] = p[e] / Zs;
    }
}

// ---------- aux loss: single block reduction ----------
__global__ __launch_bounds__(256) void moe_stats_kernel(
    const float* __restrict__ wm, const float* __restrict__ probs,
    float* __restrict__ out_aux)
{
    __shared__ float sc[E_], sp[E_];
    int tid = threadIdx.x;
    if (tid < E_) { sc[tid] = 0.f; sp[tid] = 0.f; }
    __syncthreads();
    float c[E_] = {}, p[E_] = {};
    for (int t = tid; t < BT_; t += 256) {
#pragma unroll
        for (int e = 0; e < E_; ++e) {
            if (wm[t * E_ + e] > 0.f) c[e] += 1.f;
            p[e] += probs[t * E_ + e];
        }
    }
#pragma unroll
    for (int e = 0; e < E_; ++e) { atomicAdd(&sc[e], c[e]); atomicAdd(&sp[e], p[e]); }
    __syncthreads();
    if (tid == 0) {
        float s = 0.f;
        for (int e = 0; e < E_; ++e)
            s += (sc[e] / (float)BT_) * (sp[e] / (float)BT_);
        out_aux[0] = (float)E_ * s;
    }
}

// ---------- bf16 MFMA GEMM, z-batched over experts ----------
// A: M x K bf16 (per-expert stride sAe). W: N x K bf16 (stride sWe).
// OUT: 0 = fp32 store, 1 = bf16 store, 2 = atomicAdd(out, val*wm[t, eoff+z])
template<int ACT, bool BIAS, int OUT>
__global__ __launch_bounds__(256) void mfma_gemm_kernel(
    const u16* __restrict__ A, size_t sAe, int lda,
    const u16* __restrict__ W, size_t sWe, int ldw,
    const float* __restrict__ bias, int sBe,
    void* __restrict__ Cp, size_t sCe, int ldc,
    const float* __restrict__ wmv, int eoff, int K)
{
    const int z = blockIdx.z;
    A += (size_t)z * sAe;
    W += (size_t)z * sWe;
    if (BIAS) bias += (size_t)z * sBe;

    __shared__ u16 As[64 * 64];
    __shared__ u16 Bs[64 * 64];
    const int tid  = threadIdx.x;
    const int wave = tid >> 6;
    const int lane = tid & 63;
    const int quad = lane >> 4;
    const int r16  = lane & 15;
    const int bm = blockIdx.y * 64;
    const int bn = blockIdx.x * 64;
    const int wm_ = (wave >> 1) * 32;
    const int wn = (wave & 1) * 32;

    const int s0 = tid, s1 = 256 + tid;
    const int r0 = s0 >> 3, q0 = (s0 & 7) ^ (r0 & 7);
    const int r1 = s1 >> 3, q1 = (s1 & 7) ^ (r1 & 7);
    const u16* Ag0 = A + (size_t)(bm + r0) * lda + q0 * 8;
    const u16* Ag1 = A + (size_t)(bm + r1) * lda + q1 * 8;
    const u16* Wg0 = W + (size_t)(bn + r0) * ldw + q0 * 8;
    const u16* Wg1 = W + (size_t)(bn + r1) * ldw + q1 * 8;
    u16* Al0 = As + wave * 512;
    u16* Al1 = As + 2048 + wave * 512;
    u16* Bl0 = Bs + wave * 512;
    u16* Bl1 = Bs + 2048 + wave * 512;

    f32x4 acc[2][2];
    const f32x4 zero = {0.f, 0.f, 0.f, 0.f};
    acc[0][0] = zero; acc[0][1] = zero; acc[1][0] = zero; acc[1][1] = zero;

    for (int k0 = 0; k0 < K; k0 += 64) {
        gload_lds16(Ag0 + k0, Al0);
        gload_lds16(Ag1 + k0, Al1);
        gload_lds16(Wg0 + k0, Bl0);
        gload_lds16(Wg1 + k0, Bl1);
        __syncthreads();
#pragma unroll
        for (int ks = 0; ks < 2; ++ks) {
            bf16x8 af[2], bfr[2];
#pragma unroll
            for (int mi = 0; mi < 2; ++mi) {
                int row = wm_ + mi * 16 + r16;
                int p = (ks * 4 + quad) ^ (row & 7);
                af[mi] = *(const bf16x8*)(As + row * 64 + p * 8);
            }
#pragma unroll
            for (int ni = 0; ni < 2; ++ni) {
                int row = wn + ni * 16 + r16;
                int p = (ks * 4 + quad) ^ (row & 7);
                bfr[ni] = *(const bf16x8*)(Bs + row * 64 + p * 8);
            }
#pragma unroll
            for (int mi = 0; mi < 2; ++mi)
#pragma unroll
                for (int ni = 0; ni < 2; ++ni)
                    acc[mi][ni] = __builtin_amdgcn_mfma_f32_16x16x32_bf16(
                        af[mi], bfr[ni], acc[mi][ni], 0, 0, 0);
        }
        __syncthreads();
    }

#pragma unroll
    for (int mi = 0; mi < 2; ++mi) {
#pragma unroll
        for (int vv = 0; vv < 4; ++vv) {
            int m = bm + wm_ + mi * 16 + quad * 4 + vv;
            float wmval = (OUT == 2) ? wmv[m * E_ + eoff + z] : 0.f;
#pragma unroll
            for (int ni = 0; ni < 2; ++ni) {
                int n = bn + wn + ni * 16 + r16;
                float val = acc[mi][ni][vv];
                if (BIAS) val += bias[n];
                if (ACT == 1) val = gelu_f(val);
                if (OUT == 0) {
                    ((float*)Cp + (size_t)z * sCe)[(size_t)m * ldc + n] = val;
                } else if (OUT == 1) {
                    ((u16*)Cp + (size_t)z * sCe)[(size_t)m * ldc + n] = f2bf(val);
                } else {
                    if (wmval != 0.f)
                        atomicAdd(&((float*)Cp)[(size_t)m * ldc + n], val * wmval);
                }
            }
        }
    }
}

// ---------- fp32 GEMM for dt-proj (K=32), z-batched, softplus+bias ----------
__global__ __launch_bounds__(256) void dt_gemm_kernel(
    const float* __restrict__ proj, const float* __restrict__ dtw,
    const float* __restrict__ dtb, float* __restrict__ delta)
{
    const int z = blockIdx.z;
    const float* A = proj + (size_t)z * BT_ * 64;
    const float* W = dtw + (size_t)z * DI_ * DTR_;
    const float* bias = dtb + (size_t)z * DI_;
    float* C = delta + (size_t)z * BT_ * DI_;

    __shared__ float As[16][68];
    __shared__ float Ws[16][68];
    const int bm = blockIdx.y * 64, bn = blockIdx.x * 64;
    const int tid = threadIdx.x;
    const int tx = tid & 15, ty = tid >> 4;
    const int lm = tid >> 2, lk = (tid & 3) * 4;

    const float* Ap = A + (size_t)(bm + lm) * 64 + lk;
    const float* Wp = W + (size_t)(bn + lm) * DTR_ + lk;

    float acc[4][4] = {};
    for (int k0 = 0; k0 < DTR_; k0 += 16) {
        float4 av = *(const float4*)(Ap + k0);
        float4 wv = *(const float4*)(Wp + k0);
        __syncthreads();
        As[lk + 0][lm] = av.x; As[lk + 1][lm] = av.y;
        As[lk + 2][lm] = av.z; As[lk + 3][lm] = av.w;
        Ws[lk + 0][lm] = wv.x; Ws[lk + 1][lm] = wv.y;
        Ws[lk + 2][lm] = wv.z; Ws[lk + 3][lm] = wv.w;
        __syncthreads();
#pragma unroll
        for (int k = 0; k < 16; ++k) {
            float4 a = *(const float4*)&As[k][ty * 4];
            float4 w = *(const float4*)&Ws[k][tx * 4];
            acc[0][0] += a.x * w.x; acc[0][1] += a.x * w.y; acc[0][2] += a.x * w.z; acc[0][3] += a.x * w.w;
            acc[1][0] += a.y * w.x; acc[1][1] += a.y * w.y; acc[1][2] += a.y * w.z; acc[1][3] += a.y * w.w;
            acc[2][0] += a.z * w.x; acc[2][1] += a.z * w.y; acc[2][2] += a.z * w.z; acc[2][3] += a.z * w.w;
            acc[3][0] += a.w * w.x; acc[3][1] += a.w * w.y; acc[3][2] += a.w * w.z; acc[3][3] += a.w * w.w;
        }
    }
#pragma unroll
    for (int i = 0; i < 4; ++i) {
        int m = bm + ty * 4 + i;
#pragma unroll
        for (int j = 0; j < 4; ++j) {
            int n = bn + tx * 4 + j;
            C[(size_t)m * DI_ + n] = softplus_f(acc[i][j] + bias[n]);
        }
    }
}

// ---------- depthwise causal conv k=7 + bias + gelu, bf16 in/out, z-batched ----------
__global__ __launch_bounds__(256) void dwconv7_kernel(
    const u16* __restrict__ h, const float* __restrict__ w,
    const float* __restrict__ bias, u16* __restrict__ g)
{
    int idx = blockIdx.x * 256 + threadIdx.x;    // [0, 4*BT*DI)
    int z = idx >> 20;
    int r = idx & ((1 << 20) - 1);
    int c = r & (DI_ - 1);
    int t = (r >> 10) & (T_ - 1);
    const u16* hp = h + (size_t)z * BT_ * DI_ + r;
    const float* wp = w + (size_t)z * DI_ * 7 + c * 7;
    float acc = bias[(size_t)z * DI_ + c];
#pragma unroll
    for (int j = 0; j < 7; ++j) {
        int tt = t - 6 + j;
        if (tt >= 0) acc += bf2f(hp[(j - 6) * DI_]) * wp[j];
    }
    g[idx] = f2bf(gelu_f(acc));
}

// ---------- depthwise causal conv k=4 + bias + silu, reads uz bf16, z-batched ----------
__global__ __launch_bounds__(256) void dwconv4_kernel(
    const u16* __restrict__ uz, const float* __restrict__ w,
    const float* __restrict__ bias, u16* __restrict__ uc)
{
    int idx = blockIdx.x * 256 + threadIdx.x;    // [0, 4*BT*DI)
    int z = idx >> 20;
    int r = idx & ((1 << 20) - 1);
    int c = r & (DI_ - 1);
    int bt = r >> 10;
    int t = bt & (T_ - 1);
    const u16* up = uz + (size_t)z * BT_ * 2048 + (size_t)bt * 2048 + c;
    const float* wp = w + (size_t)z * DI_ * 4 + c * 4;
    float acc = bias[(size_t)z * DI_ + c];
#pragma unroll
    for (int j = 0; j < 4; ++j) {
        int tt = t - 3 + j;
        if (tt >= 0) acc += bf2f(up[(j - 3) * 2048]) * wp[j];
    }
    uc[idx] = f2bf(silu_f(acc));
}

// ---------- chunked selective scan, z-batched (blockIdx.y = expert) ----------
// inner gid = ((b*NC + c)*DI + d)*16 + s
__global__ __launch_bounds__(256) void scan1_kernel(
    const float* __restrict__ delta, const u16* __restrict__ uc,
    const float* __restrict__ proj, const float* __restrict__ Alog,
    float2* __restrict__ PH)
{
    int z = blockIdx.y;
    int gid = blockIdx.x * 256 + threadIdx.x;
    int s = gid & 15;
    int d = (gid >> 4) & (DI_ - 1);
    int c = (gid >> 14) & (NC_ - 1);
    int b = gid >> 18;
    float A = -__expf(Alog[(size_t)z * DI_ * DS_ + d * DS_ + s]);
    int t0 = c * LCH_;
    const float* dp = delta + (size_t)z * BT_ * DI_ + ((size_t)b * T_ + t0) * DI_ + d;
    const u16*   up = uc    + (size_t)z * BT_ * DI_ + ((size_t)b * T_ + t0) * DI_ + d;
    const float* pp = proj  + (size_t)z * BT_ * 64 + ((size_t)b * T_ + t0) * 64;
    float h = 0.f, Pr = 1.f;
#pragma unroll 4
    for (int t = 0; t < LCH_; ++t) {
        float del = dp[(size_t)t * DI_];
        float uv  = bf2f(up[(size_t)t * DI_]);
        float Bv  = pp[t * 64 + DTR_ + s];
        float dA = __expf(del * A);
        h = dA * h + del * Bv * uv;
        Pr *= dA;
    }
    PH[(size_t)z * (B_ * NC_ * DI_ * 16) + gid] = make_float2(Pr, h);
}

__global__ __launch_bounds__(256) void scan_mid_kernel(
    const float2* __restrict__ PH, float* __restrict__ H)
{
    int gid = blockIdx.x * 256 + threadIdx.x;   // (z, b, ds16)
    int z = gid >> 15;
    int r = gid & 32767;
    int b = r >> 14;
    int ds16 = r & 16383;
    float h = 0.f;
    for (int c = 0; c < NC_; ++c) {
        size_t idx = (size_t)z * (B_ * NC_ * DI_ * 16) + ((size_t)(b * NC_ + c)) * (DI_ * 16) + ds16;
        H[idx] = h;
        float2 ph = PH[idx];
        h = ph.y + ph.x * h;
    }
}

// scan2 + fused silu(z) gating -> yb bf16
__global__ __launch_bounds__(256) void scan2_kernel(
    const float* __restrict__ delta, const u16* __restrict__ uc,
    const float* __restrict__ proj, const float* __restrict__ Alog,
    const float* __restrict__ Dm, const float* __restrict__ H,
    const u16* __restrict__ uz, u16* __restrict__ yb)
{
    int z = blockIdx.y;
    int gid = blockIdx.x * 256 + threadIdx.x;
    int s = gid & 15;
    int d = (gid >> 4) & (DI_ - 1);
    int c = (gid >> 14) & (NC_ - 1);
    int b = gid >> 18;
    float A = -__expf(Alog[(size_t)z * DI_ * DS_ + d * DS_ + s]);
    float Dd = Dm[(size_t)z * DI_ + d];
    int t0 = c * LCH_;
    const float* dp = delta + (size_t)z * BT_ * DI_ + ((size_t)b * T_ + t0) * DI_ + d;
    const u16*   up = uc    + (size_t)z * BT_ * DI_ + ((size_t)b * T_ + t0) * DI_ + d;
    const float* pp = proj  + (size_t)z * BT_ * 64 + ((size_t)b * T_ + t0) * 64;
    const u16*   zp = uz    + (size_t)z * BT_ * 2048 + ((size_t)b * T_ + t0) * 2048 + DI_ + d;
    u16* yp = yb + (size_t)z * BT_ * DI_ + ((size_t)b * T_ + t0) * DI_ + d;
    float h = H[(size_t)z * (B_ * NC_ * DI_ * 16) + gid];
#pragma unroll 4
    for (int t = 0; t < LCH_; ++t) {
        float del = dp[(size_t)t * DI_];
        float uv  = bf2f(up[(size_t)t * DI_]);
        float Bv  = pp[t * 64 + DTR_ + s];
        float Cv  = pp[t * 64 + DTR_ + DS_ + s];
        float dA = __expf(del * A);
        h = dA * h + del * Bv * uv;
        float p = h * Cv;
#pragma unroll
        for (int o = 8; o > 0; o >>= 1) p += __shfl_down(p, o, 16);
        if (s == 0) {
            float zval = bf2f(zp[(size_t)t * 2048]);
            yp[(size_t)t * DI_] = f2bf((p + uv * Dd) * silu_f(zval));
        }
    }
}

extern "C" void kernel_launch(void* const* d_in, const int* in_sizes, int n_in,
                              void* d_out, int out_size, void* d_ws, size_t ws_size,
                              hipStream_t stream)
{
    const float* x      = (const float*)d_in[0];
    const float* norm_w = (const float*)d_in[1];
    const float* gate_w = (const float*)d_in[2];
    const float* ent_w  = (const float*)d_in[3];
    const float* ent_b  = (const float*)d_in[4];
    const float* temp   = (const float*)d_in[5];
    const float* cfi_w  = (const float*)d_in[6];
    const float* cfi_b  = (const float*)d_in[7];
    const float* cdw_w  = (const float*)d_in[8];
    const float* cdw_b  = (const float*)d_in[9];
    const float* cfo_w  = (const float*)d_in[10];
    const float* cfo_b  = (const float*)d_in[11];
    const float* min_w  = (const float*)d_in[12];
    const float* mcw    = (const float*)d_in[13];
    const float* mcb    = (const float*)d_in[14];
    const float* mxp    = (const float*)d_in[15];
    const float* mdtw   = (const float*)d_in[16];
    const float* mdtb   = (const float*)d_in[17];
    const float* mAlog  = (const float*)d_in[18];
    const float* mD     = (const float*)d_in[19];
    const float* mow    = (const float*)d_in[20];

    float* out = (float*)d_out;

    char* wp = (char*)d_ws;
    auto alloc = [&](size_t bytes) { char* r = wp; wp += (bytes + 255) & ~(size_t)255; return r; };

    float* xn    = (float*)alloc((size_t)BTD_ * 4);
    u16*   xnb   = (u16*)  alloc((size_t)BTD_ * 2);
    float* v     = (float*)alloc(BT_ * 4);
    float* ent   = (float*)alloc(BT_ * 4);
    float* wm    = (float*)alloc(BT_ * E_ * 4);
    float* probs = (float*)alloc(BT_ * E_ * 4);
    // bf16 weight pool: cfi | cfo | min | mxp | mow
    u16* wpool = (u16*)alloc((size_t)10747904 * 2);
    u16* cfi_b16 = wpool;
    u16* cfo_b16 = wpool + 2097152;
    u16* min_b16 = wpool + 4194304;
    u16* mxp_b16 = wpool + 8388608;
    u16* mow_b16 = wpool + 8650752;

    // shared conv/mamba pool (conv phase finishes before mamba writes begin)
    char* pool = alloc((size_t)77 * 1024 * 1024);
    // conv phase
    u16* hb = (u16*)pool;                                   // 4*BT*DI bf16 = 8MB
    u16* gb = (u16*)(pool + (size_t)8 * 1024 * 1024);       // 8MB
    // mamba phase (aliases conv buffers)
    u16*    uzb  = (u16*)pool;                                        // 16MB
    u16*    ucb  = (u16*)(pool + (size_t)16 * 1024 * 1024);           // 8MB
    float*  proj = (float*)(pool + (size_t)24 * 1024 * 1024);         // 1MB
    float*  delta= (float*)(pool + (size_t)25 * 1024 * 1024);         // 16MB
    u16*    yb   = (u16*)(pool + (size_t)41 * 1024 * 1024);           // 8MB
    float2* sPH  = (float2*)(pool + (size_t)49 * 1024 * 1024);        // 16MB
    float*  sH   = (float*)(pool + (size_t)65 * 1024 * 1024);         // 8MB

    // residual into out
    hipMemcpyAsync(out, x, (size_t)BTD_ * sizeof(float), hipMemcpyDeviceToDevice, stream);

    convert_weights_kernel<<<(CB4_ + 255) / 256, 256, 0, stream>>>(
        (const float4*)cfi_w, (const float4*)cfo_w, (const float4*)min_w,
        (const float4*)mxp, (const float4*)mow, wpool);

    rmsnorm_kernel<<<BT_, 256, 0, stream>>>(x, norm_w, xn, xnb, v);
    entropy_kernel<<<B_, 512, 0, stream>>>(v, ent);
    gating_kernel<<<BT_ / 4, 256, 0, stream>>>(xn, gate_w, ent_w, ent_b, temp, ent, wm, probs);
    moe_stats_kernel<<<1, 256, 0, stream>>>(wm, probs, out + BTD_);

    const int NE4 = 4 * BT_ * DI_ / 256;     // 16384 blocks
    const int NSC = B_ * NC_ * DI_ * 16 / 256;   // 2048 blocks per expert

    // ---- conv experts (z = expert) ----
    mfma_gemm_kernel<1, true, 1><<<dim3(DI_ / 64, BT_ / 64, 4), 256, 0, stream>>>(
        xnb, 0, D_, cfi_b16, (size_t)DI_ * D_, D_, cfi_b, DI_,
        hb, (size_t)BT_ * DI_, DI_, nullptr, 0, D_);
    dwconv7_kernel<<<NE4, 256, 0, stream>>>(hb, cdw_w, cdw_b, gb);
    mfma_gemm_kernel<0, true, 2><<<dim3(D_ / 64, BT_ / 64, 4), 256, 0, stream>>>(
        gb, (size_t)BT_ * DI_, DI_, cfo_b16, (size_t)D_ * DI_, DI_, cfo_b, D_,
        out, 0, D_, wm, 0, DI_);

    // ---- mamba experts (z = expert) ----
    mfma_gemm_kernel<0, false, 1><<<dim3(2048 / 64, BT_ / 64, 4), 256, 0, stream>>>(
        xnb, 0, D_, min_b16, (size_t)2048 * D_, D_, nullptr, 0,
        uzb, (size_t)BT_ * 2048, 2048, nullptr, 0, D_);
    dwconv4_kernel<<<NE4, 256, 0, stream>>>(uzb, mcw, mcb, ucb);
    mfma_gemm_kernel<0, false, 0><<<dim3(64 / 64, BT_ / 64, 4), 256, 0, stream>>>(
        ucb, (size_t)BT_ * DI_, DI_, mxp_b16, (size_t)64 * DI_, DI_, nullptr, 0,
        proj, (size_t)BT_ * 64, 64, nullptr, 0, DI_);
    dt_gemm_kernel<<<dim3(DI_ / 64, BT_ / 64, 4), 256, 0, stream>>>(
        proj, mdtw, mdtb, delta);
    scan1_kernel<<<dim3(NSC, 4), 256, 0, stream>>>(delta, ucb, proj, mAlog, sPH);
    scan_mid_kernel<<<4 * B_ * DI_ * 16 / 256, 256, 0, stream>>>(sPH, sH);
    scan2_kernel<<<dim3(NSC, 4), 256, 0, stream>>>(
        delta, ucb, proj, mAlog, mD, sH, uzb, yb);
    mfma_gemm_kernel<0, false, 2><<<dim3(D_ / 64, BT_ / 64, 4), 256, 0, stream>>>(
        yb, (size_t)BT_ * DI_, DI_, mow_b16, (size_t)D_ * DI_, DI_, nullptr, 0,
        out, 0, D_, wm, 4, DI_);
}

// Round 4
// 428.298 us; speedup vs baseline: 5.0537x; 1.1253x over previous
//
#include <hip/hip_runtime.h>
#include <math.h>

#define B_    2
#define T_    512
#define D_    512
#define E_    8
#define DI_   1024
#define DS_   16
#define DTR_  32
#define WIN_  64
#define BT_   (B_*T_)
#define BTD_  (BT_*D_)
#define NC_   16
#define LCH_  32    // T_/NC_

typedef unsigned short u16;
typedef __attribute__((ext_vector_type(8))) short bf16x8;
typedef __attribute__((ext_vector_type(4))) float f32x4;

// ---------- helpers ----------
__device__ __forceinline__ float gelu_f(float x) {
    float x3 = x * x * x;
    return 0.5f * x * (1.0f + tanhf(0.7978845608028654f * (x + 0.044715f * x3)));
}
__device__ __forceinline__ float silu_f(float x) {
    return x / (1.0f + __expf(-x));
}
__device__ __forceinline__ float softplus_f(float x) {
    return (x > 20.0f) ? x : log1pf(__expf(x));
}
__device__ __forceinline__ u16 f2bf(float x) {
    union { float f; unsigned u; } v; v.f = x;
    unsigned r = v.u + 0x7fffu + ((v.u >> 16) & 1u);
    return (u16)(r >> 16);
}
__device__ __forceinline__ float bf2f(u16 x) {
    union { unsigned u; float f; } v; v.u = ((unsigned)x) << 16; return v.f;
}
__device__ __forceinline__ void gload_lds16(const u16* g, u16* l) {
    __builtin_amdgcn_global_load_lds((const __attribute__((address_space(1))) void*)g,
                                     (__attribute__((address_space(3))) void*)l, 16, 0, 0);
}

// ---------- merged weight convert: cfi|cfo|min|mxp|mow -> one bf16 pool ----------
#define CB0_ 524288
#define CB1_ 1048576
#define CB2_ 2097152
#define CB3_ 2162688
#define CB4_ 2686976
__global__ __launch_bounds__(256) void convert_weights_kernel(
    const float4* __restrict__ s0, const float4* __restrict__ s1,
    const float4* __restrict__ s2, const float4* __restrict__ s3,
    const float4* __restrict__ s4, u16* __restrict__ dst)
{
    int i = blockIdx.x * 256 + threadIdx.x;
    if (i >= CB4_) return;
    const float4* src; int off;
    if      (i < CB0_) { src = s0; off = i; }
    else if (i < CB1_) { src = s1; off = i - CB0_; }
    else if (i < CB2_) { src = s2; off = i - CB1_; }
    else if (i < CB3_) { src = s3; off = i - CB2_; }
    else               { src = s4; off = i - CB3_; }
    float4 v = src[off];
    ushort4 o;
    o.x = f2bf(v.x); o.y = f2bf(v.y); o.z = f2bf(v.z); o.w = f2bf(v.w);
    *(ushort4*)(dst + (size_t)i * 4) = o;
}

// ---------- RMSNorm + bf16 copy + per-token mean (v) ----------
__global__ __launch_bounds__(256) void rmsnorm_kernel(
    const float* __restrict__ x, const float* __restrict__ nw,
    float* __restrict__ xn, u16* __restrict__ xnb, float* __restrict__ v)
{
    int t = blockIdx.x;
    const float* xr = x + (size_t)t * D_;
    float s = 0.f;
    for (int i = threadIdx.x; i < D_; i += 256) { float a = xr[i]; s += a * a; }
    __shared__ float sb[4];
    __shared__ float sb2[4];
    for (int o = 32; o > 0; o >>= 1) s += __shfl_down(s, o);
    if ((threadIdx.x & 63) == 0) sb[threadIdx.x >> 6] = s;
    __syncthreads();
    float tot = sb[0] + sb[1] + sb[2] + sb[3];
    float scale = rsqrtf(tot / (float)D_ + 1e-6f);
    float vs = 0.f;
    for (int i = threadIdx.x; i < D_; i += 256) {
        float a = xr[i] * scale * nw[i];
        xn[(size_t)t * D_ + i] = a;
        xnb[(size_t)t * D_ + i] = f2bf(a);
        vs += a;
    }
    for (int o = 32; o > 0; o >>= 1) vs += __shfl_down(vs, o);
    if ((threadIdx.x & 63) == 0) sb2[threadIdx.x >> 6] = vs;
    __syncthreads();
    if (threadIdx.x == 0) v[t] = (sb2[0] + sb2[1] + sb2[2] + sb2[3]) / (float)D_;
}

// ---------- spectral entropy: parallel prefix scan, 512 threads per batch ----------
__global__ __launch_bounds__(512) void entropy_kernel(
    const float* __restrict__ v, float* __restrict__ ent)
{
    int b = blockIdx.x;
    int t = threadIdx.x;
    __shared__ float a1[T_], a2[T_];
    float x = v[b * T_ + t];
    a1[t] = x; a2[t] = x * x;
    __syncthreads();
    for (int off = 1; off < T_; off <<= 1) {
        float t1 = (t >= off) ? a1[t - off] : 0.f;
        float t2 = (t >= off) ? a2[t - off] : 0.f;
        __syncthreads();
        a1[t] += t1; a2[t] += t2;
        __syncthreads();
    }
    float p1 = (t >= WIN_) ? a1[t - WIN_] : 0.f;
    float p2 = (t >= WIN_) ? a2[t - WIN_] : 0.f;
    float mu  = (a1[t] - p1) / (float)WIN_;
    float mu2 = (a2[t] - p2) / (float)WIN_;
    float var = fmaxf(mu2 - mu * mu, 0.f);
    ent[b * T_ + t] = (logf(var + 1e-6f) + 10.f) / 20.f;
}

// ---------- gating: one wave per token, no global atomics ----------
__global__ __launch_bounds__(256) void gating_kernel(
    const float* __restrict__ xn, const float* __restrict__ gw,
    const float* __restrict__ ew, const float* __restrict__ eb,
    const float* __restrict__ temp, const float* __restrict__ ent,
    float* __restrict__ wm, float* __restrict__ probs)
{
    int wave = threadIdx.x >> 6, lane = threadIdx.x & 63;
    int t = blockIdx.x * 4 + wave;
    const float* xr = xn + (size_t)t * D_;
    float l[E_];
#pragma unroll
    for (int e = 0; e < E_; ++e) {
        float s = 0.f;
        for (int i = lane; i < D_; i += 64) s += xr[i] * gw[e * D_ + i];
#pragma unroll
        for (int o = 32; o > 0; o >>= 1) s += __shfl_down(s, o);
        l[e] = s;
    }
    if (lane == 0) {
        float ev = ent[t];
        float ts = 1.f / (fabsf(temp[0]) + 1e-6f);
#pragma unroll
        for (int e = 0; e < E_; ++e) l[e] = (l[e] + ev * ew[e] + eb[e]) * ts;
        int i1 = 0;
        for (int e = 1; e < E_; ++e) if (l[e] > l[i1]) i1 = e;
        int i2 = -1;
        for (int e = 0; e < E_; ++e) { if (e == i1) continue; if (i2 < 0 || l[e] > l[i2]) i2 = e; }
        float e2 = __expf(l[i2] - l[i1]);
        float Z = 1.f + e2;
#pragma unroll
        for (int e = 0; e < E_; ++e) wm[t * E_ + e] = 0.f;
        wm[t * E_ + i1] = 1.f / Z;
        wm[t * E_ + i2] = e2 / Z;
        float mm = l[0];
        for (int e = 1; e < E_; ++e) mm = fmaxf(mm, l[e]);
        float Zs = 0.f; float p[E_];
#pragma unroll
        for (int e = 0; e < E_; ++e) { p[e] = __expf(l[e] - mm); Zs += p[e]; }
#pragma unroll
        for (int e = 0; e < E_; ++e) probs[t * E_ + e] = p[e] / Zs;
    }
}

// ---------- aux loss: single block reduction ----------
__global__ __launch_bounds__(256) void moe_stats_kernel(
    const float* __restrict__ wm, const float* __restrict__ probs,
    float* __restrict__ out_aux)
{
    __shared__ float sc[E_], sp[E_];
    int tid = threadIdx.x;
    if (tid < E_) { sc[tid] = 0.f; sp[tid] = 0.f; }
    __syncthreads();
    float c[E_] = {}, p[E_] = {};
    for (int t = tid; t < BT_; t += 256) {
#pragma unroll
        for (int e = 0; e < E_; ++e) {
            if (wm[t * E_ + e] > 0.f) c[e] += 1.f;
            p[e] += probs[t * E_ + e];
        }
    }
#pragma unroll
    for (int e = 0; e < E_; ++e) { atomicAdd(&sc[e], c[e]); atomicAdd(&sp[e], p[e]); }
    __syncthreads();
    if (tid == 0) {
        float s = 0.f;
        for (int e = 0; e < E_; ++e)
            s += (sc[e] / (float)BT_) * (sp[e] / (float)BT_);
        out_aux[0] = (float)E_ * s;
    }
}

// ---------- bf16 MFMA GEMM, z-batched over experts ----------
// A: M x K bf16 (per-expert stride sAe). W: N x K bf16 (stride sWe).
// OUT: 0 = fp32 store, 1 = bf16 store, 2 = atomicAdd(out, val*wm[t, eoff+z])
template<int ACT, bool BIAS, int OUT>
__global__ __launch_bounds__(256) void mfma_gemm_kernel(
    const u16* __restrict__ A, size_t sAe, int lda,
    const u16* __restrict__ W, size_t sWe, int ldw,
    const float* __restrict__ bias, int sBe,
    void* __restrict__ Cp, size_t sCe, int ldc,
    const float* __restrict__ wmv, int eoff, int K)
{
    const int z = blockIdx.z;
    A += (size_t)z * sAe;
    W += (size_t)z * sWe;
    if (BIAS) bias += (size_t)z * sBe;

    __shared__ u16 As[64 * 64];
    __shared__ u16 Bs[64 * 64];
    const int tid  = threadIdx.x;
    const int wave = tid >> 6;
    const int lane = tid & 63;
    const int quad = lane >> 4;
    const int r16  = lane & 15;
    const int bm = blockIdx.y * 64;
    const int bn = blockIdx.x * 64;
    const int wm_ = (wave >> 1) * 32;
    const int wn = (wave & 1) * 32;

    const int s0 = tid, s1 = 256 + tid;
    const int r0 = s0 >> 3, q0 = (s0 & 7) ^ (r0 & 7);
    const int r1 = s1 >> 3, q1 = (s1 & 7) ^ (r1 & 7);
    const u16* Ag0 = A + (size_t)(bm + r0) * lda + q0 * 8;
    const u16* Ag1 = A + (size_t)(bm + r1) * lda + q1 * 8;
    const u16* Wg0 = W + (size_t)(bn + r0) * ldw + q0 * 8;
    const u16* Wg1 = W + (size_t)(bn + r1) * ldw + q1 * 8;
    u16* Al0 = As + wave * 512;
    u16* Al1 = As + 2048 + wave * 512;
    u16* Bl0 = Bs + wave * 512;
    u16* Bl1 = Bs + 2048 + wave * 512;

    f32x4 acc[2][2];
    const f32x4 zero = {0.f, 0.f, 0.f, 0.f};
    acc[0][0] = zero; acc[0][1] = zero; acc[1][0] = zero; acc[1][1] = zero;

    for (int k0 = 0; k0 < K; k0 += 64) {
        gload_lds16(Ag0 + k0, Al0);
        gload_lds16(Ag1 + k0, Al1);
        gload_lds16(Wg0 + k0, Bl0);
        gload_lds16(Wg1 + k0, Bl1);
        __syncthreads();
#pragma unroll
        for (int ks = 0; ks < 2; ++ks) {
            bf16x8 af[2], bfr[2];
#pragma unroll
            for (int mi = 0; mi < 2; ++mi) {
                int row = wm_ + mi * 16 + r16;
                int p = (ks * 4 + quad) ^ (row & 7);
                af[mi] = *(const bf16x8*)(As + row * 64 + p * 8);
            }
#pragma unroll
            for (int ni = 0; ni < 2; ++ni) {
                int row = wn + ni * 16 + r16;
                int p = (ks * 4 + quad) ^ (row & 7);
                bfr[ni] = *(const bf16x8*)(Bs + row * 64 + p * 8);
            }
#pragma unroll
            for (int mi = 0; mi < 2; ++mi)
#pragma unroll
                for (int ni = 0; ni < 2; ++ni)
                    acc[mi][ni] = __builtin_amdgcn_mfma_f32_16x16x32_bf16(
                        af[mi], bfr[ni], acc[mi][ni], 0, 0, 0);
        }
        __syncthreads();
    }

#pragma unroll
    for (int mi = 0; mi < 2; ++mi) {
#pragma unroll
        for (int vv = 0; vv < 4; ++vv) {
            int m = bm + wm_ + mi * 16 + quad * 4 + vv;
            float wmval = (OUT == 2) ? wmv[m * E_ + eoff + z] : 0.f;
#pragma unroll
            for (int ni = 0; ni < 2; ++ni) {
                int n = bn + wn + ni * 16 + r16;
                float val = acc[mi][ni][vv];
                if (BIAS) val += bias[n];
                if (ACT == 1) val = gelu_f(val);
                if (OUT == 0) {
                    ((float*)Cp + (size_t)z * sCe)[(size_t)m * ldc + n] = val;
                } else if (OUT == 1) {
                    ((u16*)Cp + (size_t)z * sCe)[(size_t)m * ldc + n] = f2bf(val);
                } else {
                    if (wmval != 0.f)
                        atomicAdd(&((float*)Cp)[(size_t)m * ldc + n], val * wmval);
                }
            }
        }
    }
}

// ---------- fp32 GEMM for dt-proj (K=32), z-batched, softplus+bias ----------
__global__ __launch_bounds__(256) void dt_gemm_kernel(
    const float* __restrict__ proj, const float* __restrict__ dtw,
    const float* __restrict__ dtb, float* __restrict__ delta)
{
    const int z = blockIdx.z;
    const float* A = proj + (size_t)z * BT_ * 64;
    const float* W = dtw + (size_t)z * DI_ * DTR_;
    const float* bias = dtb + (size_t)z * DI_;
    float* C = delta + (size_t)z * BT_ * DI_;

    __shared__ float As[16][68];
    __shared__ float Ws[16][68];
    const int bm = blockIdx.y * 64, bn = blockIdx.x * 64;
    const int tid = threadIdx.x;
    const int tx = tid & 15, ty = tid >> 4;
    const int lm = tid >> 2, lk = (tid & 3) * 4;

    const float* Ap = A + (size_t)(bm + lm) * 64 + lk;
    const float* Wp = W + (size_t)(bn + lm) * DTR_ + lk;

    float acc[4][4] = {};
    for (int k0 = 0; k0 < DTR_; k0 += 16) {
        float4 av = *(const float4*)(Ap + k0);
        float4 wv = *(const float4*)(Wp + k0);
        __syncthreads();
        As[lk + 0][lm] = av.x; As[lk + 1][lm] = av.y;
        As[lk + 2][lm] = av.z; As[lk + 3][lm] = av.w;
        Ws[lk + 0][lm] = wv.x; Ws[lk + 1][lm] = wv.y;
        Ws[lk + 2][lm] = wv.z; Ws[lk + 3][lm] = wv.w;
        __syncthreads();
#pragma unroll
        for (int k = 0; k < 16; ++k) {
            float4 a = *(const float4*)&As[k][ty * 4];
            float4 w = *(const float4*)&Ws[k][tx * 4];
            acc[0][0] += a.x * w.x; acc[0][1] += a.x * w.y; acc[0][2] += a.x * w.z; acc[0][3] += a.x * w.w;
            acc[1][0] += a.y * w.x; acc[1][1] += a.y * w.y; acc[1][2] += a.y * w.z; acc[1][3] += a.y * w.w;
            acc[2][0] += a.z * w.x; acc[2][1] += a.z * w.y; acc[2][2] += a.z * w.z; acc[2][3] += a.z * w.w;
            acc[3][0] += a.w * w.x; acc[3][1] += a.w * w.y; acc[3][2] += a.w * w.z; acc[3][3] += a.w * w.w;
        }
    }
#pragma unroll
    for (int i = 0; i < 4; ++i) {
        int m = bm + ty * 4 + i;
#pragma unroll
        for (int j = 0; j < 4; ++j) {
            int n = bn + tx * 4 + j;
            C[(size_t)m * DI_ + n] = softplus_f(acc[i][j] + bias[n]);
        }
    }
}

// ---------- depthwise causal conv k=7 + bias + gelu, bf16 in/out, z-batched ----------
__global__ __launch_bounds__(256) void dwconv7_kernel(
    const u16* __restrict__ h, const float* __restrict__ w,
    const float* __restrict__ bias, u16* __restrict__ g)
{
    int idx = blockIdx.x * 256 + threadIdx.x;    // [0, 4*BT*DI)
    int z = idx >> 20;
    int r = idx & ((1 << 20) - 1);
    int c = r & (DI_ - 1);
    int t = (r >> 10) & (T_ - 1);
    const u16* hp = h + (size_t)z * BT_ * DI_ + r;
    const float* wp = w + (size_t)z * DI_ * 7 + c * 7;
    float acc = bias[(size_t)z * DI_ + c];
#pragma unroll
    for (int j = 0; j < 7; ++j) {
        int tt = t - 6 + j;
        if (tt >= 0) acc += bf2f(hp[(j - 6) * DI_]) * wp[j];
    }
    g[idx] = f2bf(gelu_f(acc));
}

// ---------- depthwise causal conv k=4 + bias + silu, reads uz bf16, z-batched ----------
__global__ __launch_bounds__(256) void dwconv4_kernel(
    const u16* __restrict__ uz, const float* __restrict__ w,
    const float* __restrict__ bias, u16* __restrict__ uc)
{
    int idx = blockIdx.x * 256 + threadIdx.x;    // [0, 4*BT*DI)
    int z = idx >> 20;
    int r = idx & ((1 << 20) - 1);
    int c = r & (DI_ - 1);
    int bt = r >> 10;
    int t = bt & (T_ - 1);
    const u16* up = uz + (size_t)z * BT_ * 2048 + (size_t)bt * 2048 + c;
    const float* wp = w + (size_t)z * DI_ * 4 + c * 4;
    float acc = bias[(size_t)z * DI_ + c];
#pragma unroll
    for (int j = 0; j < 4; ++j) {
        int tt = t - 3 + j;
        if (tt >= 0) acc += bf2f(up[(j - 3) * 2048]) * wp[j];
    }
    uc[idx] = f2bf(silu_f(acc));
}

// ---------- chunked selective scan: one thread per (b, chunk, d), 16 states in regs ----------
// thread gid = (b*NC + c)*DI + d ; PH layout: [z][b*NC+c][d][s] float2
__global__ __launch_bounds__(256) void scan1_kernel(
    const float* __restrict__ delta, const u16* __restrict__ uc,
    const float* __restrict__ proj, const float* __restrict__ Alog,
    float2* __restrict__ PH)
{
    int z = blockIdx.y;
    int gid = blockIdx.x * 256 + threadIdx.x;
    int d = gid & (DI_ - 1);
    int c = (gid >> 10) & (NC_ - 1);
    int b = gid >> 14;
    float A[DS_];
    {
        const float* Ap = Alog + (size_t)z * DI_ * DS_ + d * DS_;
        float4 a0 = *(const float4*)(Ap + 0);
        float4 a1 = *(const float4*)(Ap + 4);
        float4 a2 = *(const float4*)(Ap + 8);
        float4 a3 = *(const float4*)(Ap + 12);
        *(float4*)&A[0] = a0; *(float4*)&A[4] = a1;
        *(float4*)&A[8] = a2; *(float4*)&A[12] = a3;
#pragma unroll
        for (int s = 0; s < DS_; ++s) A[s] = -__expf(A[s]);
    }
    int t0 = c * LCH_;
    const float* dp = delta + (size_t)z * BT_ * DI_ + ((size_t)b * T_ + t0) * DI_ + d;
    const u16*   up = uc    + (size_t)z * BT_ * DI_ + ((size_t)b * T_ + t0) * DI_ + d;
    const float* pp = proj  + (size_t)z * BT_ * 64 + ((size_t)b * T_ + t0) * 64;
    float h[DS_], P[DS_];
#pragma unroll
    for (int s = 0; s < DS_; ++s) { h[s] = 0.f; P[s] = 1.f; }
#pragma unroll 2
    for (int t = 0; t < LCH_; ++t) {
        float del = dp[(size_t)t * DI_];
        float uv  = bf2f(up[(size_t)t * DI_]);
        float du  = del * uv;
        float Bv[DS_];
        const float4* p4 = (const float4*)(pp + t * 64 + 32);
        *(float4*)&Bv[0] = p4[0]; *(float4*)&Bv[4]  = p4[1];
        *(float4*)&Bv[8] = p4[2]; *(float4*)&Bv[12] = p4[3];
#pragma unroll
        for (int s = 0; s < DS_; ++s) {
            float dA = __expf(del * A[s]);
            h[s] = dA * h[s] + du * Bv[s];
            P[s] *= dA;
        }
    }
    float2* o = PH + (size_t)z * (B_ * NC_ * DI_ * 16) + (size_t)(b * NC_ + c) * (DI_ * 16) + (size_t)d * 16;
#pragma unroll
    for (int s = 0; s < DS_; ++s) o[s] = make_float2(P[s], h[s]);
}

__global__ __launch_bounds__(256) void scan_mid_kernel(
    const float2* __restrict__ PH, float* __restrict__ H)
{
    int gid = blockIdx.x * 256 + threadIdx.x;   // (z, b, ds16)
    int z = gid >> 15;
    int r = gid & 32767;
    int b = r >> 14;
    int ds16 = r & 16383;
    float h = 0.f;
    for (int c = 0; c < NC_; ++c) {
        size_t idx = (size_t)z * (B_ * NC_ * DI_ * 16) + ((size_t)(b * NC_ + c)) * (DI_ * 16) + ds16;
        H[idx] = h;
        float2 ph = PH[idx];
        h = ph.y + ph.x * h;
    }
}

// scan2: replay with correct h0, fused C-reduction + silu(z) gate -> yb bf16
__global__ __launch_bounds__(256) void scan2_kernel(
    const float* __restrict__ delta, const u16* __restrict__ uc,
    const float* __restrict__ proj, const float* __restrict__ Alog,
    const float* __restrict__ Dm, const float* __restrict__ H,
    const u16* __restrict__ uz, u16* __restrict__ yb)
{
    int z = blockIdx.y;
    int gid = blockIdx.x * 256 + threadIdx.x;
    int d = gid & (DI_ - 1);
    int c = (gid >> 10) & (NC_ - 1);
    int b = gid >> 14;
    float A[DS_];
    {
        const float* Ap = Alog + (size_t)z * DI_ * DS_ + d * DS_;
        float4 a0 = *(const float4*)(Ap + 0);
        float4 a1 = *(const float4*)(Ap + 4);
        float4 a2 = *(const float4*)(Ap + 8);
        float4 a3 = *(const float4*)(Ap + 12);
        *(float4*)&A[0] = a0; *(float4*)&A[4] = a1;
        *(float4*)&A[8] = a2; *(float4*)&A[12] = a3;
#pragma unroll
        for (int s = 0; s < DS_; ++s) A[s] = -__expf(A[s]);
    }
    float Dd = Dm[(size_t)z * DI_ + d];
    float h[DS_];
    {
        const float* Hp = H + (size_t)z * (B_ * NC_ * DI_ * 16) + (size_t)(b * NC_ + c) * (DI_ * 16) + (size_t)d * 16;
        float4 h0 = *(const float4*)(Hp + 0);
        float4 h1 = *(const float4*)(Hp + 4);
        float4 h2 = *(const float4*)(Hp + 8);
        float4 h3 = *(const float4*)(Hp + 12);
        *(float4*)&h[0] = h0; *(float4*)&h[4] = h1;
        *(float4*)&h[8] = h2; *(float4*)&h[12] = h3;
    }
    int t0 = c * LCH_;
    const float* dp = delta + (size_t)z * BT_ * DI_ + ((size_t)b * T_ + t0) * DI_ + d;
    const u16*   up = uc    + (size_t)z * BT_ * DI_ + ((size_t)b * T_ + t0) * DI_ + d;
    const float* pp = proj  + (size_t)z * BT_ * 64 + ((size_t)b * T_ + t0) * 64;
    const u16*   zp = uz    + (size_t)z * BT_ * 2048 + ((size_t)b * T_ + t0) * 2048 + DI_ + d;
    u16* yp = yb + (size_t)z * BT_ * DI_ + ((size_t)b * T_ + t0) * DI_ + d;
#pragma unroll 2
    for (int t = 0; t < LCH_; ++t) {
        float del = dp[(size_t)t * DI_];
        float uv  = bf2f(up[(size_t)t * DI_]);
        float du  = del * uv;
        float Bv[DS_], Cv[DS_];
        const float4* p4 = (const float4*)(pp + t * 64 + 32);
        *(float4*)&Bv[0] = p4[0]; *(float4*)&Bv[4]  = p4[1];
        *(float4*)&Bv[8] = p4[2]; *(float4*)&Bv[12] = p4[3];
        *(float4*)&Cv[0] = p4[4]; *(float4*)&Cv[4]  = p4[5];
        *(float4*)&Cv[8] = p4[6]; *(float4*)&Cv[12] = p4[7];
        float y = 0.f;
#pragma unroll
        for (int s = 0; s < DS_; ++s) {
            float dA = __expf(del * A[s]);
            h[s] = dA * h[s] + du * Bv[s];
            y += h[s] * Cv[s];
        }
        y += uv * Dd;
        float zval = bf2f(zp[(size_t)t * 2048]);
        yp[(size_t)t * DI_] = f2bf(y * silu_f(zval));
    }
}

extern "C" void kernel_launch(void* const* d_in, const int* in_sizes, int n_in,
                              void* d_out, int out_size, void* d_ws, size_t ws_size,
                              hipStream_t stream)
{
    const float* x      = (const float*)d_in[0];
    const float* norm_w = (const float*)d_in[1];
    const float* gate_w = (const float*)d_in[2];
    const float* ent_w  = (const float*)d_in[3];
    const float* ent_b  = (const float*)d_in[4];
    const float* temp   = (const float*)d_in[5];
    const float* cfi_w  = (const float*)d_in[6];
    const float* cfi_b  = (const float*)d_in[7];
    const float* cdw_w  = (const float*)d_in[8];
    const float* cdw_b  = (const float*)d_in[9];
    const float* cfo_w  = (const float*)d_in[10];
    const float* cfo_b  = (const float*)d_in[11];
    const float* min_w  = (const float*)d_in[12];
    const float* mcw    = (const float*)d_in[13];
    const float* mcb    = (const float*)d_in[14];
    const float* mxp    = (const float*)d_in[15];
    const float* mdtw   = (const float*)d_in[16];
    const float* mdtb   = (const float*)d_in[17];
    const float* mAlog  = (const float*)d_in[18];
    const float* mD     = (const float*)d_in[19];
    const float* mow    = (const float*)d_in[20];

    float* out = (float*)d_out;

    char* wp = (char*)d_ws;
    auto alloc = [&](size_t bytes) { char* r = wp; wp += (bytes + 255) & ~(size_t)255; return r; };

    float* xn    = (float*)alloc((size_t)BTD_ * 4);
    u16*   xnb   = (u16*)  alloc((size_t)BTD_ * 2);
    float* v     = (float*)alloc(BT_ * 4);
    float* ent   = (float*)alloc(BT_ * 4);
    float* wm    = (float*)alloc(BT_ * E_ * 4);
    float* probs = (float*)alloc(BT_ * E_ * 4);
    // bf16 weight pool: cfi | cfo | min | mxp | mow
    u16* wpool = (u16*)alloc((size_t)10747904 * 2);
    u16* cfi_b16 = wpool;
    u16* cfo_b16 = wpool + 2097152;
    u16* min_b16 = wpool + 4194304;
    u16* mxp_b16 = wpool + 8388608;
    u16* mow_b16 = wpool + 8650752;

    // shared conv/mamba pool (conv phase finishes before mamba writes begin)
    char* pool = alloc((size_t)77 * 1024 * 1024);
    // conv phase
    u16* hb = (u16*)pool;                                   // 4*BT*DI bf16 = 8MB
    u16* gb = (u16*)(pool + (size_t)8 * 1024 * 1024);       // 8MB
    // mamba phase (aliases conv buffers)
    u16*    uzb  = (u16*)pool;                                        // 16MB
    u16*    ucb  = (u16*)(pool + (size_t)16 * 1024 * 1024);           // 8MB
    float*  proj = (float*)(pool + (size_t)24 * 1024 * 1024);         // 1MB
    float*  delta= (float*)(pool + (size_t)25 * 1024 * 1024);         // 16MB
    u16*    yb   = (u16*)(pool + (size_t)41 * 1024 * 1024);           // 8MB
    float2* sPH  = (float2*)(pool + (size_t)49 * 1024 * 1024);        // 16MB
    float*  sH   = (float*)(pool + (size_t)65 * 1024 * 1024);         // 8MB

    // residual into out
    hipMemcpyAsync(out, x, (size_t)BTD_ * sizeof(float), hipMemcpyDeviceToDevice, stream);

    convert_weights_kernel<<<(CB4_ + 255) / 256, 256, 0, stream>>>(
        (const float4*)cfi_w, (const float4*)cfo_w, (const float4*)min_w,
        (const float4*)mxp, (const float4*)mow, wpool);

    rmsnorm_kernel<<<BT_, 256, 0, stream>>>(x, norm_w, xn, xnb, v);
    entropy_kernel<<<B_, 512, 0, stream>>>(v, ent);
    gating_kernel<<<BT_ / 4, 256, 0, stream>>>(xn, gate_w, ent_w, ent_b, temp, ent, wm, probs);
    moe_stats_kernel<<<1, 256, 0, stream>>>(wm, probs, out + BTD_);

    const int NE4 = 4 * BT_ * DI_ / 256;     // 16384 blocks
    const int NSC = B_ * NC_ * DI_ / 256;    // 128 blocks per expert (16 states/thread)

    // ---- conv experts (z = expert) ----
    mfma_gemm_kernel<1, true, 1><<<dim3(DI_ / 64, BT_ / 64, 4), 256, 0, stream>>>(
        xnb, 0, D_, cfi_b16, (size_t)DI_ * D_, D_, cfi_b, DI_,
        hb, (size_t)BT_ * DI_, DI_, nullptr, 0, D_);
    dwconv7_kernel<<<NE4, 256, 0, stream>>>(hb, cdw_w, cdw_b, gb);
    mfma_gemm_kernel<0, true, 2><<<dim3(D_ / 64, BT_ / 64, 4), 256, 0, stream>>>(
        gb, (size_t)BT_ * DI_, DI_, cfo_b16, (size_t)D_ * DI_, DI_, cfo_b, D_,
        out, 0, D_, wm, 0, DI_);

    // ---- mamba experts (z = expert) ----
    mfma_gemm_kernel<0, false, 1><<<dim3(2048 / 64, BT_ / 64, 4), 256, 0, stream>>>(
        xnb, 0, D_, min_b16, (size_t)2048 * D_, D_, nullptr, 0,
        uzb, (size_t)BT_ * 2048, 2048, nullptr, 0, D_);
    dwconv4_kernel<<<NE4, 256, 0, stream>>>(uzb, mcw, mcb, ucb);
    mfma_gemm_kernel<0, false, 0><<<dim3(64 / 64, BT_ / 64, 4), 256, 0, stream>>>(
        ucb, (size_t)BT_ * DI_, DI_, mxp_b16, (size_t)64 * DI_, DI_, nullptr, 0,
        proj, (size_t)BT_ * 64, 64, nullptr, 0, DI_);
    dt_gemm_kernel<<<dim3(DI_ / 64, BT_ / 64, 4), 256, 0, stream>>>(
        proj, mdtw, mdtb, delta);
    scan1_kernel<<<dim3(NSC, 4), 256, 0, stream>>>(delta, ucb, proj, mAlog, sPH);
    scan_mid_kernel<<<4 * B_ * DI_ * 16 / 256, 256, 0, stream>>>(sPH, sH);
    scan2_kernel<<<dim3(NSC, 4), 256, 0, stream>>>(
        delta, ucb, proj, mAlog, mD, sH, uzb, yb);
    mfma_gemm_kernel<0, false, 2><<<dim3(D_ / 64, BT_ / 64, 4), 256, 0, stream>>>(
        yb, (size_t)BT_ * DI_, DI_, mow_b16, (size_t)D_ * DI_, DI_, nullptr, 0,
        out, 0, D_, wm, 4, DI_);
}

// Round 5
// 396.336 us; speedup vs baseline: 5.4613x; 1.0806x over previous
//
#include <hip/hip_runtime.h>
#include <math.h>

#define B_    2
#define T_    512
#define D_    512
#define E_    8
#define DI_   1024
#define DS_   16
#define DTR_  32
#define WIN_  64
#define BT_   (B_*T_)
#define BTD_  (BT_*D_)
#define NC_   16
#define LCH_  32    // T_/NC_

typedef unsigned short u16;
typedef __attribute__((ext_vector_type(8))) short bf16x8;
typedef __attribute__((ext_vector_type(4))) float f32x4;

// ---------- helpers ----------
__device__ __forceinline__ float gelu_f(float x) {
    float x3 = x * x * x;
    return 0.5f * x * (1.0f + tanhf(0.7978845608028654f * (x + 0.044715f * x3)));
}
__device__ __forceinline__ float silu_f(float x) {
    return x / (1.0f + __expf(-x));
}
__device__ __forceinline__ float softplus_f(float x) {
    return (x > 20.0f) ? x : log1pf(__expf(x));
}
__device__ __forceinline__ u16 f2bf(float x) {
    union { float f; unsigned u; } v; v.f = x;
    unsigned r = v.u + 0x7fffu + ((v.u >> 16) & 1u);
    return (u16)(r >> 16);
}
__device__ __forceinline__ float bf2f(u16 x) {
    union { unsigned u; float f; } v; v.u = ((unsigned)x) << 16; return v.f;
}
__device__ __forceinline__ void gload_lds16(const u16* g, u16* l) {
    __builtin_amdgcn_global_load_lds((const __attribute__((address_space(1))) void*)g,
                                     (__attribute__((address_space(3))) void*)l, 16, 0, 0);
}

// ---------- merged weight convert: cfi|cfo|min|mxp|mow -> one bf16 pool ----------
#define CB0_ 524288
#define CB1_ 1048576
#define CB2_ 2097152
#define CB3_ 2162688
#define CB4_ 2686976
__global__ __launch_bounds__(256) void convert_weights_kernel(
    const float4* __restrict__ s0, const float4* __restrict__ s1,
    const float4* __restrict__ s2, const float4* __restrict__ s3,
    const float4* __restrict__ s4, u16* __restrict__ dst)
{
    int i = blockIdx.x * 256 + threadIdx.x;
    if (i >= CB4_) return;
    const float4* src; int off;
    if      (i < CB0_) { src = s0; off = i; }
    else if (i < CB1_) { src = s1; off = i - CB0_; }
    else if (i < CB2_) { src = s2; off = i - CB1_; }
    else if (i < CB3_) { src = s3; off = i - CB2_; }
    else               { src = s4; off = i - CB3_; }
    float4 v = src[off];
    ushort4 o;
    o.x = f2bf(v.x); o.y = f2bf(v.y); o.z = f2bf(v.z); o.w = f2bf(v.w);
    *(ushort4*)(dst + (size_t)i * 4) = o;
}

// ---------- RMSNorm + bf16 copy + per-token mean (v) ----------
__global__ __launch_bounds__(256) void rmsnorm_kernel(
    const float* __restrict__ x, const float* __restrict__ nw,
    float* __restrict__ xn, u16* __restrict__ xnb, float* __restrict__ v)
{
    int t = blockIdx.x;
    const float* xr = x + (size_t)t * D_;
    float s = 0.f;
    for (int i = threadIdx.x; i < D_; i += 256) { float a = xr[i]; s += a * a; }
    __shared__ float sb[4];
    __shared__ float sb2[4];
    for (int o = 32; o > 0; o >>= 1) s += __shfl_down(s, o);
    if ((threadIdx.x & 63) == 0) sb[threadIdx.x >> 6] = s;
    __syncthreads();
    float tot = sb[0] + sb[1] + sb[2] + sb[3];
    float scale = rsqrtf(tot / (float)D_ + 1e-6f);
    float vs = 0.f;
    for (int i = threadIdx.x; i < D_; i += 256) {
        float a = xr[i] * scale * nw[i];
        xn[(size_t)t * D_ + i] = a;
        xnb[(size_t)t * D_ + i] = f2bf(a);
        vs += a;
    }
    for (int o = 32; o > 0; o >>= 1) vs += __shfl_down(vs, o);
    if ((threadIdx.x & 63) == 0) sb2[threadIdx.x >> 6] = vs;
    __syncthreads();
    if (threadIdx.x == 0) v[t] = (sb2[0] + sb2[1] + sb2[2] + sb2[3]) / (float)D_;
}

// ---------- spectral entropy: parallel prefix scan, 512 threads per batch ----------
__global__ __launch_bounds__(512) void entropy_kernel(
    const float* __restrict__ v, float* __restrict__ ent)
{
    int b = blockIdx.x;
    int t = threadIdx.x;
    __shared__ float a1[T_], a2[T_];
    float x = v[b * T_ + t];
    a1[t] = x; a2[t] = x * x;
    __syncthreads();
    for (int off = 1; off < T_; off <<= 1) {
        float t1 = (t >= off) ? a1[t - off] : 0.f;
        float t2 = (t >= off) ? a2[t - off] : 0.f;
        __syncthreads();
        a1[t] += t1; a2[t] += t2;
        __syncthreads();
    }
    float p1 = (t >= WIN_) ? a1[t - WIN_] : 0.f;
    float p2 = (t >= WIN_) ? a2[t - WIN_] : 0.f;
    float mu  = (a1[t] - p1) / (float)WIN_;
    float mu2 = (a2[t] - p2) / (float)WIN_;
    float var = fmaxf(mu2 - mu * mu, 0.f);
    ent[b * T_ + t] = (logf(var + 1e-6f) + 10.f) / 20.f;
}

// ---------- gating: one wave per token, no global atomics ----------
__global__ __launch_bounds__(256) void gating_kernel(
    const float* __restrict__ xn, const float* __restrict__ gw,
    const float* __restrict__ ew, const float* __restrict__ eb,
    const float* __restrict__ temp, const float* __restrict__ ent,
    float* __restrict__ wm, float* __restrict__ probs)
{
    int wave = threadIdx.x >> 6, lane = threadIdx.x & 63;
    int t = blockIdx.x * 4 + wave;
    const float* xr = xn + (size_t)t * D_;
    float l[E_];
#pragma unroll
    for (int e = 0; e < E_; ++e) {
        float s = 0.f;
        for (int i = lane; i < D_; i += 64) s += xr[i] * gw[e * D_ + i];
#pragma unroll
        for (int o = 32; o > 0; o >>= 1) s += __shfl_down(s, o);
        l[e] = s;
    }
    if (lane == 0) {
        float ev = ent[t];
        float ts = 1.f / (fabsf(temp[0]) + 1e-6f);
#pragma unroll
        for (int e = 0; e < E_; ++e) l[e] = (l[e] + ev * ew[e] + eb[e]) * ts;
        int i1 = 0;
        for (int e = 1; e < E_; ++e) if (l[e] > l[i1]) i1 = e;
        int i2 = -1;
        for (int e = 0; e < E_; ++e) { if (e == i1) continue; if (i2 < 0 || l[e] > l[i2]) i2 = e; }
        float e2 = __expf(l[i2] - l[i1]);
        float Z = 1.f + e2;
#pragma unroll
        for (int e = 0; e < E_; ++e) wm[t * E_ + e] = 0.f;
        wm[t * E_ + i1] = 1.f / Z;
        wm[t * E_ + i2] = e2 / Z;
        float mm = l[0];
        for (int e = 1; e < E_; ++e) mm = fmaxf(mm, l[e]);
        float Zs = 0.f; float p[E_];
#pragma unroll
        for (int e = 0; e < E_; ++e) { p[e] = __expf(l[e] - mm); Zs += p[e]; }
#pragma unroll
        for (int e = 0; e < E_; ++e) probs[t * E_ + e] = p[e] / Zs;
    }
}

// ---------- aux loss: single block reduction ----------
__global__ __launch_bounds__(256) void moe_stats_kernel(
    const float* __restrict__ wm, const float* __restrict__ probs,
    float* __restrict__ out_aux)
{
    __shared__ float sc[E_], sp[E_];
    int tid = threadIdx.x;
    if (tid < E_) { sc[tid] = 0.f; sp[tid] = 0.f; }
    __syncthreads();
    float c[E_] = {}, p[E_] = {};
    for (int t = tid; t < BT_; t += 256) {
#pragma unroll
        for (int e = 0; e < E_; ++e) {
            if (wm[t * E_ + e] > 0.f) c[e] += 1.f;
            p[e] += probs[t * E_ + e];
        }
    }
#pragma unroll
    for (int e = 0; e < E_; ++e) { atomicAdd(&sc[e], c[e]); atomicAdd(&sp[e], p[e]); }
    __syncthreads();
    if (tid == 0) {
        float s = 0.f;
        for (int e = 0; e < E_; ++e)
            s += (sc[e] / (float)BT_) * (sp[e] / (float)BT_);
        out_aux[0] = (float)E_ * s;
    }
}

// ---------- bf16 MFMA GEMM, z-batched over experts ----------
// A: M x K bf16 (per-expert stride sAe). W: N x K bf16 (stride sWe).
// OUT: 0 = fp32 store, 1 = bf16 store, 2 = atomicAdd(out, val*wm[t, eoff+z]),
//      3 = plain fp32 atomicAdd (for split-K)
template<int ACT, bool BIAS, int OUT, int SPLITK = 1>
__global__ __launch_bounds__(256) void mfma_gemm_kernel(
    const u16* __restrict__ A, size_t sAe, int lda,
    const u16* __restrict__ W, size_t sWe, int ldw,
    const float* __restrict__ bias, int sBe,
    void* __restrict__ Cp, size_t sCe, int ldc,
    const float* __restrict__ wmv, int eoff, int K)
{
    int z, ks;
    if (SPLITK > 1) { z = blockIdx.z / SPLITK; ks = blockIdx.z % SPLITK; }
    else            { z = blockIdx.z; ks = 0; }
    A += (size_t)z * sAe;
    W += (size_t)z * sWe;
    if (BIAS) bias += (size_t)z * sBe;

    __shared__ u16 As[64 * 64];
    __shared__ u16 Bs[64 * 64];
    const int tid  = threadIdx.x;
    const int wave = tid >> 6;
    const int lane = tid & 63;
    const int quad = lane >> 4;
    const int r16  = lane & 15;
    const int bm = blockIdx.y * 64;
    const int bn = blockIdx.x * 64;
    const int wm_ = (wave >> 1) * 32;
    const int wn = (wave & 1) * 32;

    const int s0 = tid, s1 = 256 + tid;
    const int r0 = s0 >> 3, q0 = (s0 & 7) ^ (r0 & 7);
    const int r1 = s1 >> 3, q1 = (s1 & 7) ^ (r1 & 7);
    const u16* Ag0 = A + (size_t)(bm + r0) * lda + q0 * 8;
    const u16* Ag1 = A + (size_t)(bm + r1) * lda + q1 * 8;
    const u16* Wg0 = W + (size_t)(bn + r0) * ldw + q0 * 8;
    const u16* Wg1 = W + (size_t)(bn + r1) * ldw + q1 * 8;
    u16* Al0 = As + wave * 512;
    u16* Al1 = As + 2048 + wave * 512;
    u16* Bl0 = Bs + wave * 512;
    u16* Bl1 = Bs + 2048 + wave * 512;

    f32x4 acc[2][2];
    const f32x4 zero = {0.f, 0.f, 0.f, 0.f};
    acc[0][0] = zero; acc[0][1] = zero; acc[1][0] = zero; acc[1][1] = zero;

    const int kBeg = ks * (K / SPLITK);
    const int kEnd = kBeg + K / SPLITK;
    for (int k0 = kBeg; k0 < kEnd; k0 += 64) {
        gload_lds16(Ag0 + k0, Al0);
        gload_lds16(Ag1 + k0, Al1);
        gload_lds16(Wg0 + k0, Bl0);
        gload_lds16(Wg1 + k0, Bl1);
        __syncthreads();
#pragma unroll
        for (int kss = 0; kss < 2; ++kss) {
            bf16x8 af[2], bfr[2];
#pragma unroll
            for (int mi = 0; mi < 2; ++mi) {
                int row = wm_ + mi * 16 + r16;
                int p = (kss * 4 + quad) ^ (row & 7);
                af[mi] = *(const bf16x8*)(As + row * 64 + p * 8);
            }
#pragma unroll
            for (int ni = 0; ni < 2; ++ni) {
                int row = wn + ni * 16 + r16;
                int p = (kss * 4 + quad) ^ (row & 7);
                bfr[ni] = *(const bf16x8*)(Bs + row * 64 + p * 8);
            }
#pragma unroll
            for (int mi = 0; mi < 2; ++mi)
#pragma unroll
                for (int ni = 0; ni < 2; ++ni)
                    acc[mi][ni] = __builtin_amdgcn_mfma_f32_16x16x32_bf16(
                        af[mi], bfr[ni], acc[mi][ni], 0, 0, 0);
        }
        __syncthreads();
    }

#pragma unroll
    for (int mi = 0; mi < 2; ++mi) {
#pragma unroll
        for (int vv = 0; vv < 4; ++vv) {
            int m = bm + wm_ + mi * 16 + quad * 4 + vv;
            float wmval = (OUT == 2) ? wmv[m * E_ + eoff + z] : 0.f;
#pragma unroll
            for (int ni = 0; ni < 2; ++ni) {
                int n = bn + wn + ni * 16 + r16;
                float val = acc[mi][ni][vv];
                if (BIAS) val += bias[n];
                if (ACT == 1) val = gelu_f(val);
                if (OUT == 0) {
                    ((float*)Cp + (size_t)z * sCe)[(size_t)m * ldc + n] = val;
                } else if (OUT == 1) {
                    ((u16*)Cp + (size_t)z * sCe)[(size_t)m * ldc + n] = f2bf(val);
                } else if (OUT == 2) {
                    if (wmval != 0.f)
                        atomicAdd(&((float*)Cp)[(size_t)m * ldc + n], val * wmval);
                } else {
                    atomicAdd(&((float*)Cp + (size_t)z * sCe)[(size_t)m * ldc + n], val);
                }
            }
        }
    }
}

// ---------- fp32 GEMM for dt-proj (K=32), z-batched, softplus+bias ----------
__global__ __launch_bounds__(256) void dt_gemm_kernel(
    const float* __restrict__ proj, const float* __restrict__ dtw,
    const float* __restrict__ dtb, float* __restrict__ delta)
{
    const int z = blockIdx.z;
    const float* A = proj + (size_t)z * BT_ * 64;
    const float* W = dtw + (size_t)z * DI_ * DTR_;
    const float* bias = dtb + (size_t)z * DI_;
    float* C = delta + (size_t)z * BT_ * DI_;

    __shared__ float As[16][68];
    __shared__ float Ws[16][68];
    const int bm = blockIdx.y * 64, bn = blockIdx.x * 64;
    const int tid = threadIdx.x;
    const int tx = tid & 15, ty = tid >> 4;
    const int lm = tid >> 2, lk = (tid & 3) * 4;

    const float* Ap = A + (size_t)(bm + lm) * 64 + lk;
    const float* Wp = W + (size_t)(bn + lm) * DTR_ + lk;

    float acc[4][4] = {};
    for (int k0 = 0; k0 < DTR_; k0 += 16) {
        float4 av = *(const float4*)(Ap + k0);
        float4 wv = *(const float4*)(Wp + k0);
        __syncthreads();
        As[lk + 0][lm] = av.x; As[lk + 1][lm] = av.y;
        As[lk + 2][lm] = av.z; As[lk + 3][lm] = av.w;
        Ws[lk + 0][lm] = wv.x; Ws[lk + 1][lm] = wv.y;
        Ws[lk + 2][lm] = wv.z; Ws[lk + 3][lm] = wv.w;
        __syncthreads();
#pragma unroll
        for (int k = 0; k < 16; ++k) {
            float4 a = *(const float4*)&As[k][ty * 4];
            float4 w = *(const float4*)&Ws[k][tx * 4];
            acc[0][0] += a.x * w.x; acc[0][1] += a.x * w.y; acc[0][2] += a.x * w.z; acc[0][3] += a.x * w.w;
            acc[1][0] += a.y * w.x; acc[1][1] += a.y * w.y; acc[1][2] += a.y * w.z; acc[1][3] += a.y * w.w;
            acc[2][0] += a.z * w.x; acc[2][1] += a.z * w.y; acc[2][2] += a.z * w.z; acc[2][3] += a.z * w.w;
            acc[3][0] += a.w * w.x; acc[3][1] += a.w * w.y; acc[3][2] += a.w * w.z; acc[3][3] += a.w * w.w;
        }
    }
#pragma unroll
    for (int i = 0; i < 4; ++i) {
        int m = bm + ty * 4 + i;
#pragma unroll
        for (int j = 0; j < 4; ++j) {
            int n = bn + tx * 4 + j;
            C[(size_t)m * DI_ + n] = softplus_f(acc[i][j] + bias[n]);
        }
    }
}

// ---------- depthwise causal conv k=7 + bias + gelu, bf16 in/out, z-batched ----------
__global__ __launch_bounds__(256) void dwconv7_kernel(
    const u16* __restrict__ h, const float* __restrict__ w,
    const float* __restrict__ bias, u16* __restrict__ g)
{
    int idx = blockIdx.x * 256 + threadIdx.x;    // [0, 4*BT*DI)
    int z = idx >> 20;
    int r = idx & ((1 << 20) - 1);
    int c = r & (DI_ - 1);
    int t = (r >> 10) & (T_ - 1);
    const u16* hp = h + (size_t)z * BT_ * DI_ + r;
    const float* wp = w + (size_t)z * DI_ * 7 + c * 7;
    float acc = bias[(size_t)z * DI_ + c];
#pragma unroll
    for (int j = 0; j < 7; ++j) {
        int tt = t - 6 + j;
        if (tt >= 0) acc += bf2f(hp[(j - 6) * DI_]) * wp[j];
    }
    g[idx] = f2bf(gelu_f(acc));
}

// ---------- depthwise causal conv k=4 + bias + silu, reads uz bf16, z-batched ----------
__global__ __launch_bounds__(256) void dwconv4_kernel(
    const u16* __restrict__ uz, const float* __restrict__ w,
    const float* __restrict__ bias, u16* __restrict__ uc)
{
    int idx = blockIdx.x * 256 + threadIdx.x;    // [0, 4*BT*DI)
    int z = idx >> 20;
    int r = idx & ((1 << 20) - 1);
    int c = r & (DI_ - 1);
    int bt = r >> 10;
    int t = bt & (T_ - 1);
    const u16* up = uz + (size_t)z * BT_ * 2048 + (size_t)bt * 2048 + c;
    const float* wp = w + (size_t)z * DI_ * 4 + c * 4;
    float acc = bias[(size_t)z * DI_ + c];
#pragma unroll
    for (int j = 0; j < 4; ++j) {
        int tt = t - 3 + j;
        if (tt >= 0) acc += bf2f(up[(j - 3) * 2048]) * wp[j];
    }
    uc[idx] = f2bf(silu_f(acc));
}

// ---------- chunked selective scan: one thread per (b, chunk, d, s-quad) ----------
// idx = ((b*NC + c)*DI + d)*4 + sq ; PH layout: [z][b*NC+c][d][s] float2
__global__ __launch_bounds__(256) void scan1_kernel(
    const float* __restrict__ delta, const u16* __restrict__ uc,
    const float* __restrict__ proj, const float* __restrict__ Alog,
    float2* __restrict__ PH)
{
    int z = blockIdx.y;
    int idx = blockIdx.x * 256 + threadIdx.x;
    int sq = idx & 3;
    int d = (idx >> 2) & (DI_ - 1);
    int c = (idx >> 12) & (NC_ - 1);
    int b = idx >> 16;
    float A[4];
    *(float4*)A = *(const float4*)(Alog + (size_t)z * DI_ * DS_ + d * DS_ + sq * 4);
#pragma unroll
    for (int s = 0; s < 4; ++s) A[s] = -__expf(A[s]);
    int t0 = c * LCH_;
    const float* dp = delta + (size_t)z * BT_ * DI_ + ((size_t)b * T_ + t0) * DI_ + d;
    const u16*   up = uc    + (size_t)z * BT_ * DI_ + ((size_t)b * T_ + t0) * DI_ + d;
    const float* pp = proj  + (size_t)z * BT_ * 64 + ((size_t)b * T_ + t0) * 64 + 32 + sq * 4;
    float h[4] = {}, P[4] = {1.f, 1.f, 1.f, 1.f};
#pragma unroll 4
    for (int t = 0; t < LCH_; ++t) {
        float del = dp[(size_t)t * DI_];
        float uv  = bf2f(up[(size_t)t * DI_]);
        float du  = del * uv;
        float Bv[4];
        *(float4*)Bv = *(const float4*)(pp + t * 64);
#pragma unroll
        for (int s = 0; s < 4; ++s) {
            float dA = __expf(del * A[s]);
            h[s] = dA * h[s] + du * Bv[s];
            P[s] *= dA;
        }
    }
    float2* o = PH + (size_t)z * (B_ * NC_ * DI_ * 16)
              + (size_t)(b * NC_ + c) * (DI_ * 16) + (size_t)d * 16 + sq * 4;
    float4 o0 = {P[0], h[0], P[1], h[1]};
    float4 o1 = {P[2], h[2], P[3], h[3]};
    *(float4*)&o[0] = o0;
    *(float4*)&o[2] = o1;
}

__global__ __launch_bounds__(256) void scan_mid_kernel(
    const float2* __restrict__ PH, float* __restrict__ H)
{
    int gid = blockIdx.x * 256 + threadIdx.x;   // (z, b, ds16)
    int z = gid >> 15;
    int r = gid & 32767;
    int b = r >> 14;
    int ds16 = r & 16383;
    float h = 0.f;
    for (int c = 0; c < NC_; ++c) {
        size_t idx = (size_t)z * (B_ * NC_ * DI_ * 16) + ((size_t)(b * NC_ + c)) * (DI_ * 16) + ds16;
        H[idx] = h;
        float2 ph = PH[idx];
        h = ph.y + ph.x * h;
    }
}

// scan2: replay with correct h0, 4 states/thread, reduce y over 4 lanes,
// fused silu(z) gate -> yb bf16
__global__ __launch_bounds__(256) void scan2_kernel(
    const float* __restrict__ delta, const u16* __restrict__ uc,
    const float* __restrict__ proj, const float* __restrict__ Alog,
    const float* __restrict__ Dm, const float* __restrict__ H,
    const u16* __restrict__ uz, u16* __restrict__ yb)
{
    int z = blockIdx.y;
    int idx = blockIdx.x * 256 + threadIdx.x;
    int sq = idx & 3;
    int d = (idx >> 2) & (DI_ - 1);
    int c = (idx >> 12) & (NC_ - 1);
    int b = idx >> 16;
    float A[4];
    *(float4*)A = *(const float4*)(Alog + (size_t)z * DI_ * DS_ + d * DS_ + sq * 4);
#pragma unroll
    for (int s = 0; s < 4; ++s) A[s] = -__expf(A[s]);
    float Dd = Dm[(size_t)z * DI_ + d];
    float h[4];
    *(float4*)h = *(const float4*)(H + (size_t)z * (B_ * NC_ * DI_ * 16)
        + (size_t)(b * NC_ + c) * (DI_ * 16) + (size_t)d * 16 + sq * 4);
    int t0 = c * LCH_;
    const float* dp = delta + (size_t)z * BT_ * DI_ + ((size_t)b * T_ + t0) * DI_ + d;
    const u16*   up = uc    + (size_t)z * BT_ * DI_ + ((size_t)b * T_ + t0) * DI_ + d;
    const float* pp = proj  + (size_t)z * BT_ * 64 + ((size_t)b * T_ + t0) * 64 + 32 + sq * 4;
    const u16*   zp = uz    + (size_t)z * BT_ * 2048 + ((size_t)b * T_ + t0) * 2048 + DI_ + d;
    u16* yp = yb + (size_t)z * BT_ * DI_ + ((size_t)b * T_ + t0) * DI_ + d;
#pragma unroll 4
    for (int t = 0; t < LCH_; ++t) {
        float del = dp[(size_t)t * DI_];
        float uv  = bf2f(up[(size_t)t * DI_]);
        float du  = del * uv;
        float Bv[4], Cv[4];
        *(float4*)Bv = *(const float4*)(pp + t * 64);
        *(float4*)Cv = *(const float4*)(pp + t * 64 + 16);
        float y = 0.f;
#pragma unroll
        for (int s = 0; s < 4; ++s) {
            float dA = __expf(del * A[s]);
            h[s] = dA * h[s] + du * Bv[s];
            y += h[s] * Cv[s];
        }
        y += __shfl_down(y, 1, 4);
        y += __shfl_down(y, 2, 4);
        if (sq == 0) {
            y += uv * Dd;
            float zval = bf2f(zp[(size_t)t * 2048]);
            yp[(size_t)t * DI_] = f2bf(y * silu_f(zval));
        }
    }
}

extern "C" void kernel_launch(void* const* d_in, const int* in_sizes, int n_in,
                              void* d_out, int out_size, void* d_ws, size_t ws_size,
                              hipStream_t stream)
{
    const float* x      = (const float*)d_in[0];
    const float* norm_w = (const float*)d_in[1];
    const float* gate_w = (const float*)d_in[2];
    const float* ent_w  = (const float*)d_in[3];
    const float* ent_b  = (const float*)d_in[4];
    const float* temp   = (const float*)d_in[5];
    const float* cfi_w  = (const float*)d_in[6];
    const float* cfi_b  = (const float*)d_in[7];
    const float* cdw_w  = (const float*)d_in[8];
    const float* cdw_b  = (const float*)d_in[9];
    const float* cfo_w  = (const float*)d_in[10];
    const float* cfo_b  = (const float*)d_in[11];
    const float* min_w  = (const float*)d_in[12];
    const float* mcw    = (const float*)d_in[13];
    const float* mcb    = (const float*)d_in[14];
    const float* mxp    = (const float*)d_in[15];
    const float* mdtw   = (const float*)d_in[16];
    const float* mdtb   = (const float*)d_in[17];
    const float* mAlog  = (const float*)d_in[18];
    const float* mD     = (const float*)d_in[19];
    const float* mow    = (const float*)d_in[20];

    float* out = (float*)d_out;

    char* wp = (char*)d_ws;
    auto alloc = [&](size_t bytes) { char* r = wp; wp += (bytes + 255) & ~(size_t)255; return r; };

    float* xn    = (float*)alloc((size_t)BTD_ * 4);
    u16*   xnb   = (u16*)  alloc((size_t)BTD_ * 2);
    float* v     = (float*)alloc(BT_ * 4);
    float* ent   = (float*)alloc(BT_ * 4);
    float* wm    = (float*)alloc(BT_ * E_ * 4);
    float* probs = (float*)alloc(BT_ * E_ * 4);
    // bf16 weight pool: cfi | cfo | min | mxp | mow
    u16* wpool = (u16*)alloc((size_t)10747904 * 2);
    u16* cfi_b16 = wpool;
    u16* cfo_b16 = wpool + 2097152;
    u16* min_b16 = wpool + 4194304;
    u16* mxp_b16 = wpool + 8388608;
    u16* mow_b16 = wpool + 8650752;

    // shared conv/mamba pool (conv phase finishes before mamba writes begin)
    char* pool = alloc((size_t)77 * 1024 * 1024);
    // conv phase
    u16* hb = (u16*)pool;                                   // 4*BT*DI bf16 = 8MB
    u16* gb = (u16*)(pool + (size_t)8 * 1024 * 1024);       // 8MB
    // mamba phase (aliases conv buffers)
    u16*    uzb  = (u16*)pool;                                        // 16MB
    u16*    ucb  = (u16*)(pool + (size_t)16 * 1024 * 1024);           // 8MB
    float*  proj = (float*)(pool + (size_t)24 * 1024 * 1024);         // 1MB
    float*  delta= (float*)(pool + (size_t)25 * 1024 * 1024);         // 16MB
    u16*    yb   = (u16*)(pool + (size_t)41 * 1024 * 1024);           // 8MB
    float2* sPH  = (float2*)(pool + (size_t)49 * 1024 * 1024);        // 16MB
    float*  sH   = (float*)(pool + (size_t)65 * 1024 * 1024);         // 8MB

    // residual into out
    hipMemcpyAsync(out, x, (size_t)BTD_ * sizeof(float), hipMemcpyDeviceToDevice, stream);

    convert_weights_kernel<<<(CB4_ + 255) / 256, 256, 0, stream>>>(
        (const float4*)cfi_w, (const float4*)cfo_w, (const float4*)min_w,
        (const float4*)mxp, (const float4*)mow, wpool);

    rmsnorm_kernel<<<BT_, 256, 0, stream>>>(x, norm_w, xn, xnb, v);
    entropy_kernel<<<B_, 512, 0, stream>>>(v, ent);
    gating_kernel<<<BT_ / 4, 256, 0, stream>>>(xn, gate_w, ent_w, ent_b, temp, ent, wm, probs);
    moe_stats_kernel<<<1, 256, 0, stream>>>(wm, probs, out + BTD_);

    const int NE4 = 4 * BT_ * DI_ / 256;       // 16384 blocks
    const int NSC = B_ * NC_ * DI_ * 4 / 256;  // 512 blocks per expert (4 states/thread)

    // ---- conv experts (z = expert) ----
    mfma_gemm_kernel<1, true, 1><<<dim3(DI_ / 64, BT_ / 64, 4), 256, 0, stream>>>(
        xnb, 0, D_, cfi_b16, (size_t)DI_ * D_, D_, cfi_b, DI_,
        hb, (size_t)BT_ * DI_, DI_, nullptr, 0, D_);
    dwconv7_kernel<<<NE4, 256, 0, stream>>>(hb, cdw_w, cdw_b, gb);
    mfma_gemm_kernel<0, true, 2><<<dim3(D_ / 64, BT_ / 64, 4), 256, 0, stream>>>(
        gb, (size_t)BT_ * DI_, DI_, cfo_b16, (size_t)D_ * DI_, DI_, cfo_b, D_,
        out, 0, D_, wm, 0, DI_);

    // ---- mamba experts (z = expert) ----
    mfma_gemm_kernel<0, false, 1><<<dim3(2048 / 64, BT_ / 64, 4), 256, 0, stream>>>(
        xnb, 0, D_, min_b16, (size_t)2048 * D_, D_, nullptr, 0,
        uzb, (size_t)BT_ * 2048, 2048, nullptr, 0, D_);
    dwconv4_kernel<<<NE4, 256, 0, stream>>>(uzb, mcw, mcb, ucb);
    hipMemsetAsync(proj, 0, (size_t)4 * BT_ * 64 * 4, stream);
    mfma_gemm_kernel<0, false, 3, 4><<<dim3(64 / 64, BT_ / 64, 16), 256, 0, stream>>>(
        ucb, (size_t)BT_ * DI_, DI_, mxp_b16, (size_t)64 * DI_, DI_, nullptr, 0,
        proj, (size_t)BT_ * 64, 64, nullptr, 0, DI_);
    dt_gemm_kernel<<<dim3(DI_ / 64, BT_ / 64, 4), 256, 0, stream>>>(
        proj, mdtw, mdtb, delta);
    scan1_kernel<<<dim3(NSC, 4), 256, 0, stream>>>(delta, ucb, proj, mAlog, sPH);
    scan_mid_kernel<<<4 * B_ * DI_ * 16 / 256, 256, 0, stream>>>(sPH, sH);
    scan2_kernel<<<dim3(NSC, 4), 256, 0, stream>>>(
        delta, ucb, proj, mAlog, mD, sH, uzb, yb);
    mfma_gemm_kernel<0, false, 2><<<dim3(D_ / 64, BT_ / 64, 4), 256, 0, stream>>>(
        yb, (size_t)BT_ * DI_, DI_, mow_b16, (size_t)D_ * DI_, DI_, nullptr, 0,
        out, 0, D_, wm, 4, DI_);
}